// Round 16
// baseline (462.753 us; speedup 1.0000x reference)
//
#include <hip/hip_runtime.h>
#include <hip/hip_bf16.h>

// ---------- types ----------
typedef __attribute__((ext_vector_type(8))) short short8;
typedef __attribute__((ext_vector_type(4))) float f32x4;

#define EMB 128
#define OUT 256
#define NRAD 6
#define NDENSE 3
#define BSH 7                 // bucket shift: 128 nodes per bucket
#define MAXBKT 512            // >= ceil(N/128)
#define HB 128                // setup/hist blocks

static __device__ __forceinline__ unsigned short f32_to_bf16(float f) {
    union { float f; unsigned u; } v; v.f = f;
    unsigned r = v.u + 0x7fffu + ((v.u >> 16) & 1u);   // round-nearest-even
    return (unsigned short)(r >> 16);
}
static __device__ __forceinline__ float silu(float x) {
    return x / (1.f + __expf(-x));
}
static __device__ __forceinline__ void gload_lds16(const void* gp, void* lp) {
    __builtin_amdgcn_global_load_lds(
        (const __attribute__((address_space(1))) void*)gp,
        (__attribute__((address_space(3))) void*)lp, 16, 0, 0);
}

// ---------- K0: setup = bucket hist partials + weight convert + out zero ----------
__global__ __launch_bounds__(256) void setup_hist_kernel(
        const int* __restrict__ src, int* __restrict__ bpart,
        const float* __restrict__ Wup, const float* __restrict__ Wd,
        unsigned short* __restrict__ Wbf, float* __restrict__ out,
        int E, int nbkt, int outn) {
    __shared__ int h[MAXBKT];
    for (int b = threadIdx.x; b < nbkt; b += 256) h[b] = 0;
    __syncthreads();
    int gtid = blockIdx.x * blockDim.x + threadIdx.x;
    int stride = gridDim.x * blockDim.x;
    for (int e = gtid; e < E; e += stride)
        atomicAdd(&h[src[e] >> BSH], 1);
    for (int j = gtid; j < outn; j += stride) out[j] = 0.f;
    const int n1 = OUT * EMB, n2 = NDENSE * OUT * OUT;
    for (int j = gtid; j < n1 + n2; j += stride)
        Wbf[j] = f32_to_bf16(j < n1 ? Wup[j] : Wd[j - n1]);
    __syncthreads();
    int* row = bpart + (size_t)blockIdx.x * MAXBKT;
    for (int b = threadIdx.x; b < nbkt; b += 256) row[b] = h[b];
}

// ---------- K1: sum partials + scan ----------
__global__ __launch_bounds__(512) void bscan_kernel(
        const int* __restrict__ bpart, int* __restrict__ bbase,
        int* __restrict__ gcursor, int nbkt, int E) {
    __shared__ int s[MAXBKT];
    int t = threadIdx.x;
    int v = 0;
    if (t < nbkt) {
#pragma unroll 8
        for (int k = 0; k < HB; ++k) v += bpart[(size_t)k * MAXBKT + t];
    }
    s[t] = v;
    __syncthreads();
    for (int d = 1; d < MAXBKT; d <<= 1) {
        int x = (t >= d) ? s[t - d] : 0;
        __syncthreads();
        s[t] += x;
        __syncthreads();
    }
    if (t < nbkt) {
        int ex = s[t] - v;
        bbase[t] = ex;
        gcursor[t] = ex;
    }
    if (t == 0) bbase[nbkt] = E;
}

// ---------- K2: scatter edges into bucket-grouped packed pairs ----------
// pair = (e << BSH) | (src & 127)  — single int, halves pair traffic
__global__ __launch_bounds__(256) void bscatter_kernel(
        const int* __restrict__ src, int* __restrict__ gcursor,
        int* __restrict__ pairs, int E, int nbkt) {
    __shared__ int h[MAXBKT];
    __shared__ int base[MAXBKT];
    for (int b = threadIdx.x; b < nbkt; b += 256) h[b] = 0;
    __syncthreads();
    const int per = (E + gridDim.x - 1) / gridDim.x;
    const int e0 = blockIdx.x * per;
    const int e1 = min(e0 + per, E);
    for (int e = e0 + threadIdx.x; e < e1; e += 256)
        atomicAdd(&h[src[e] >> BSH], 1);
    __syncthreads();
    for (int b = threadIdx.x; b < nbkt; b += 256)
        base[b] = h[b] ? atomicAdd(&gcursor[b], h[b]) : 0;
    __syncthreads();
    for (int e = e0 + threadIdx.x; e < e1; e += 256) {
        int s = src[e];
        int pos = atomicAdd(&base[s >> BSH], 1);
        pairs[pos] = (e << BSH) | (s & ((1 << BSH) - 1));
    }
}

// ---------- K3: per-bucket local CSR (counting sort in LDS) ----------
__global__ __launch_bounds__(256) void local_csr_kernel(
        const int* __restrict__ pairs, const int* __restrict__ bbase,
        int* __restrict__ offsets, int* __restrict__ perm, int N, int E, int nbkt) {
    __shared__ int cnt[128], exc[128], cur[128];
    const int b = blockIdx.x;
    const int t = threadIdx.x;
    const int n0 = b << BSH;
    const int nn = min(128, N - n0);
    const int p0 = bbase[b], p1 = bbase[b + 1];
    if (t < 128) cnt[t] = 0;
    __syncthreads();
    for (int i = p0 + t; i < p1; i += 256)
        atomicAdd(&cnt[pairs[i] & 127], 1);
    __syncthreads();
    if (t < 128) exc[t] = cnt[t];
    __syncthreads();
    for (int d = 1; d < 128; d <<= 1) {
        int x = (t >= d && t < 128) ? exc[t - d] : 0;
        __syncthreads();
        if (t < 128) exc[t] += x;
        __syncthreads();
    }
    if (t < 128) {
        int ex = exc[t] - cnt[t];
        cur[t] = ex;
        if (t < nn) offsets[n0 + t] = p0 + ex;
    }
    if (b == 0 && t == 0) offsets[N] = E;
    __syncthreads();
    for (int i = p0 + t; i < p1; i += 256) {
        int pr = pairs[i];
        int pos = p0 + atomicAdd(&cur[pr & 127], 1);
        perm[pos] = pr >> BSH;
    }
}

// ---------- edge transform + per-node gather-sum v4 (R15 exact) ----------
__global__ __launch_bounds__(256) void edge_accum_kernel(
        const float* __restrict__ m, const float* __restrict__ rbf,
        const int* __restrict__ perm, const int* __restrict__ offsets,
        const float* __restrict__ W_rbf, uint2* __restrict__ t_pack, int N) {
    const int lane = threadIdx.x & 63;
    const int h = lane >> 5;
    const int c = lane & 31;
    const int gw = blockIdx.x * (blockDim.x >> 6) + (threadIdx.x >> 6);
    const int nwaves = gridDim.x * (blockDim.x >> 6);

    float wk[4][6];
#pragma unroll
    for (int k = 0; k < 4; ++k)
#pragma unroll
        for (int j = 0; j < 6; ++j) wk[k][j] = W_rbf[(4 * c + k) * NRAD + j];

    for (int node = gw; node < N; node += nwaves) {
        const int beg = offsets[node], end = offsets[node + 1];
        float a0 = 0.f, a1 = 0.f, a2 = 0.f, a3 = 0.f;
        int pe = 0;
        if (beg < end) {
            int pi = beg + (lane & 31); if (pi > end - 1) pi = end - 1;
            pe = perm[pi];
        }
        for (int cb = beg; cb < end; cb += 32) {
            int pe_next = 0;
            if (cb + 32 < end) {
                int pi = cb + 32 + (lane & 31); if (pi > end - 1) pi = end - 1;
                pe_next = perm[pi];
            }
#pragma unroll
            for (int p = 0; p < 16; ++p) {
                int e = __shfl(pe, 2 * p + h);
                const float2* rp = (const float2*)(rbf + (size_t)e * NRAD);
                float2 r0 = rp[0], r1 = rp[1], r2 = rp[2];
                float4 mv = *(const float4*)(m + (size_t)e * EMB + 4 * c);
                float g = (cb + 2 * p + h < end) ? 1.f : 0.f;
                float p0 = (wk[0][0]*r0.x + wk[0][1]*r0.y + wk[0][2]*r1.x
                          + wk[0][3]*r1.y + wk[0][4]*r2.x + wk[0][5]*r2.y) * g;
                float p1 = (wk[1][0]*r0.x + wk[1][1]*r0.y + wk[1][2]*r1.x
                          + wk[1][3]*r1.y + wk[1][4]*r2.x + wk[1][5]*r2.y) * g;
                float p2 = (wk[2][0]*r0.x + wk[2][1]*r0.y + wk[2][2]*r1.x
                          + wk[2][3]*r1.y + wk[2][4]*r2.x + wk[2][5]*r2.y) * g;
                float p3 = (wk[3][0]*r0.x + wk[3][1]*r0.y + wk[3][2]*r1.x
                          + wk[3][3]*r1.y + wk[3][4]*r2.x + wk[3][5]*r2.y) * g;
                a0 = fmaf(mv.x, p0, a0);
                a1 = fmaf(mv.y, p1, a1);
                a2 = fmaf(mv.z, p2, a2);
                a3 = fmaf(mv.w, p3, a3);
            }
            pe = pe_next;
        }
        a0 += __shfl_xor(a0, 32);
        a1 += __shfl_xor(a1, 32);
        a2 += __shfl_xor(a2, 32);
        a3 += __shfl_xor(a3, 32);
        if (h == 0) {
            uint2 pk;
            pk.x = (unsigned)f32_to_bf16(a0) | ((unsigned)f32_to_bf16(a1) << 16);
            pk.y = (unsigned)f32_to_bf16(a2) | ((unsigned)f32_to_bf16(a3) << 16);
            t_pack[(size_t)node * 32 + c] = pk;
        }
    }
}

// ---------- fused MLP v4: 48KB LDS (3 blocks/CU), seg-major Wbuf (no swizzle) ----------
// Wbuf[seg][col] : seg g holds every col's 16B K-group g of the current 32-K
// chunk. Stage: lane t loads row t's seg `it` -> linear dest (wave-contig).
// bf read = 16 consecutive 16B slots -> 2 lanes/bank, conflict-free.
__global__ __launch_bounds__(256) void fused_mlp2_kernel(
        const unsigned short* __restrict__ A0,    // [M,128] bf16
        const unsigned short* __restrict__ Wup,   // [256,128] bf16
        const unsigned short* __restrict__ Wd,    // [3,256,256] bf16
        const float* __restrict__ bd,             // [3,256]
        const int* __restrict__ gids,             // [M] sorted
        float* __restrict__ out, int M) {
    __shared__ char Abuf[32768];   // 64 rows x 512B (layer0: x256B)
    __shared__ char Wbuf[16384];   // 4 segs x 256 cols x 16B
    const int t    = threadIdx.x;
    const int w    = t >> 6;
    const int lane = t & 63;
    const int r    = lane & 15;
    const int g    = lane >> 4;
    const int row0 = blockIdx.x * 64;

    f32x4 acc[4][4];

    // ---- stage A0: 64 rows x 256B (pre-swizzled source, linear dest) ----
#pragma unroll
    for (int it = 0; it < 4; ++it) {
        int unit = it * 256 + t;
        int row  = unit >> 4;
        int seg  = unit & 15;
        int csrc = (seg * 16) ^ ((row & 7) << 4);
        int ga = row0 + row; if (ga >= M) ga = M - 1;
        gload_lds16((const char*)A0 + (size_t)ga * 256 + csrc, Abuf + unit * 16);
    }

    // ---- layer 0: K=128, 4 chunks of 32-K ----
#pragma unroll
    for (int i = 0; i < 4; ++i)
#pragma unroll
        for (int j = 0; j < 4; ++j) acc[i][j] = (f32x4){0.f, 0.f, 0.f, 0.f};
#pragma unroll
    for (int kci = 0; kci < 4; ++kci) {
        const int kc = kci * 32;
        if (kci) __syncthreads();          // Wbuf reads done
#pragma unroll
        for (int it = 0; it < 4; ++it)     // lane t = W row t, seg it
            gload_lds16((const char*)Wup + (size_t)t * 256 + kc * 2 + it * 16,
                        Wbuf + it * 4096 + t * 16);
        asm volatile("s_waitcnt vmcnt(0)" ::: "memory");
        __syncthreads();
        short8 af[4], bf[4];
#pragma unroll
        for (int mi = 0; mi < 4; ++mi) {
            int row = mi * 16 + r;
            int off = kc * 2 + g * 16;
            af[mi] = *(const short8*)(Abuf + row * 256 + (off ^ ((row & 7) << 4)));
        }
#pragma unroll
        for (int nj = 0; nj < 4; ++nj) {
            int col = w * 64 + nj * 16 + r;
            bf[nj] = *(const short8*)(Wbuf + g * 4096 + col * 16);
        }
#pragma unroll
        for (int mi = 0; mi < 4; ++mi)
#pragma unroll
            for (int nj = 0; nj < 4; ++nj)
                acc[mi][nj] = __builtin_amdgcn_mfma_f32_16x16x32_bf16(
                    af[mi], bf[nj], acc[mi][nj], 0, 0, 0);
    }
    __syncthreads();                        // Abuf reads done
    // write layer0 output (no bias/act) into Abuf, 512B rows
#pragma unroll
    for (int mi = 0; mi < 4; ++mi)
#pragma unroll
        for (int nj = 0; nj < 4; ++nj)
#pragma unroll
            for (int q = 0; q < 4; ++q) {
                int row = mi * 16 + g * 4 + q;
                int col = w * 64 + nj * 16 + r;
                *(unsigned short*)(Abuf + row * 512 + ((col * 2) ^ ((row & 7) << 4)))
                    = f32_to_bf16(acc[mi][nj][q]);
            }

    // ---- layers 1..3: K=256, 8 chunks of 32-K ----
    for (int ell = 0; ell < NDENSE; ++ell) {
        const unsigned short* Wl = Wd + (size_t)ell * OUT * OUT;
        const float* bias = bd + ell * OUT;
#pragma unroll
        for (int i = 0; i < 4; ++i)
#pragma unroll
            for (int j = 0; j < 4; ++j) acc[i][j] = (f32x4){0.f, 0.f, 0.f, 0.f};
#pragma unroll
        for (int kci = 0; kci < 8; ++kci) {
            const int kc = kci * 32;
            __syncthreads();               // Wbuf reads (+Abuf writes) done
#pragma unroll
            for (int it = 0; it < 4; ++it)
                gload_lds16((const char*)Wl + (size_t)t * 512 + kc * 2 + it * 16,
                            Wbuf + it * 4096 + t * 16);
            asm volatile("s_waitcnt vmcnt(0)" ::: "memory");
            __syncthreads();
            short8 af[4], bf[4];
#pragma unroll
            for (int mi = 0; mi < 4; ++mi) {
                int row = mi * 16 + r;
                int off = kc * 2 + g * 16;
                af[mi] = *(const short8*)(Abuf + row * 512 + (off ^ ((row & 7) << 4)));
            }
#pragma unroll
            for (int nj = 0; nj < 4; ++nj) {
                int col = w * 64 + nj * 16 + r;
                bf[nj] = *(const short8*)(Wbuf + g * 4096 + col * 16);
            }
#pragma unroll
            for (int mi = 0; mi < 4; ++mi)
#pragma unroll
                for (int nj = 0; nj < 4; ++nj)
                    acc[mi][nj] = __builtin_amdgcn_mfma_f32_16x16x32_bf16(
                        af[mi], bf[nj], acc[mi][nj], 0, 0, 0);
        }
        __syncthreads();                    // all Abuf reads done
        if (ell < NDENSE - 1) {
#pragma unroll
            for (int mi = 0; mi < 4; ++mi)
#pragma unroll
                for (int nj = 0; nj < 4; ++nj) {
                    int col = w * 64 + nj * 16 + r;
                    float b = bias[col];
#pragma unroll
                    for (int q = 0; q < 4; ++q) {
                        int row = mi * 16 + g * 4 + q;
                        *(unsigned short*)(Abuf + row * 512
                            + ((col * 2) ^ ((row & 7) << 4)))
                            = f32_to_bf16(silu(acc[mi][nj][q] + b));
                    }
                }
        } else {
            // ---- final layer: silu + per-graph reduce, atomicAdd into out ----
            bool uni = (row0 + 63 < M) && (gids[row0] == gids[row0 + 63]);
            if (uni) {
                int gph = gids[row0];
                float* og = out + (size_t)gph * OUT;
#pragma unroll
                for (int nj = 0; nj < 4; ++nj) {
                    int gcol = w * 64 + nj * 16 + r;
                    float b = bias[gcol];
                    float s = 0.f;
#pragma unroll
                    for (int mi = 0; mi < 4; ++mi)
#pragma unroll
                        for (int q = 0; q < 4; ++q)
                            s += silu(acc[mi][nj][q] + b);
                    s += __shfl_xor(s, 16);
                    s += __shfl_xor(s, 32);
                    if (g == 0) atomicAdd(&og[gcol], s);
                }
            } else {
#pragma unroll
                for (int nj = 0; nj < 4; ++nj) {
                    int gcol = w * 64 + nj * 16 + r;
                    float b = bias[gcol];
#pragma unroll
                    for (int mi = 0; mi < 4; ++mi)
#pragma unroll
                        for (int q = 0; q < 4; ++q) {
                            int grow = row0 + mi * 16 + g * 4 + q;
                            if (grow < M)
                                atomicAdd(&out[(size_t)gids[grow] * OUT + gcol],
                                          silu(acc[mi][nj][q] + b));
                        }
                }
            }
        }
    }
}

// ---------- host ----------
extern "C" void kernel_launch(void* const* d_in, const int* in_sizes, int n_in,
                              void* d_out, int out_size, void* d_ws, size_t ws_size,
                              hipStream_t stream) {
    const float* m         = (const float*)d_in[0];
    const float* rbf       = (const float*)d_in[1];
    const int*   src       = (const int*)d_in[2];
    const int*   gids      = (const int*)d_in[3];
    const float* W_rbf     = (const float*)d_in[4];
    const float* W_up      = (const float*)d_in[5];
    const float* W_dense   = (const float*)d_in[6];
    const float* b_dense   = (const float*)d_in[7];
    float* out = (float*)d_out;

    const int E = in_sizes[2];
    const int N = in_sizes[3];
    const int nbkt = (N + 127) >> BSH;     // 391 for N=50000

    size_t off = 0;
    auto alloc = [&](size_t bytes) -> void* {
        void* p = (char*)d_ws + off;
        off += (bytes + 255) & ~(size_t)255;
        return p;
    };
    int* bpart   = (int*)alloc((size_t)HB * MAXBKT * 4);
    int* bbase   = (int*)alloc((size_t)(MAXBKT + 1) * 4);
    int* gcursor = (int*)alloc((size_t)MAXBKT * 4);
    int* offsets = (int*)alloc(((size_t)N + 1) * 4);
    int* pairs   = (int*)alloc((size_t)E * 4);
    int* perm    = (int*)alloc((size_t)E * 4);
    unsigned short* t_bf = (unsigned short*)alloc((size_t)N * EMB * 2);
    unsigned short* Wbf  = (unsigned short*)alloc((size_t)(OUT * EMB + NDENSE * OUT * OUT) * 2);
    unsigned short* Wup_bf = Wbf;
    unsigned short* Wd_bf  = Wbf + OUT * EMB;

    // K0: setup = hist partials + weight convert + out zero (merged)
    setup_hist_kernel<<<HB, 256, 0, stream>>>(src, bpart, W_up, W_dense, Wbf,
                                              out, E, nbkt, out_size);
    // K1..K3: scan, scatter, local CSR
    bscan_kernel<<<1, MAXBKT, 0, stream>>>(bpart, bbase, gcursor, nbkt, E);
    bscatter_kernel<<<512, 256, 0, stream>>>(src, gcursor, pairs, E, nbkt);
    local_csr_kernel<<<nbkt, 256, 0, stream>>>(pairs, bbase, offsets, perm, N, E, nbkt);

    // edge transform + node gather v4
    edge_accum_kernel<<<2048, 256, 0, stream>>>(m, rbf, perm, offsets, W_rbf,
                                                (uint2*)t_bf, N);

    // fused MLP + per-graph readout (atomic into zeroed out)
    fused_mlp2_kernel<<<(N + 63) / 64, 256, 0, stream>>>(t_bf, Wup_bf, Wd_bf,
                                                         b_dense, gids, out, N);
}

// Round 17
// 424.037 us; speedup vs baseline: 1.0913x; 1.0913x over previous
//
#include <hip/hip_runtime.h>
#include <hip/hip_bf16.h>

// ---------- types ----------
typedef __attribute__((ext_vector_type(8))) short short8;
typedef __attribute__((ext_vector_type(4))) float f32x4;

#define EMB 128
#define OUT 256
#define NRAD 6
#define NDENSE 3
#define BSH 7                 // bucket shift: 128 nodes per bucket
#define MAXBKT 512            // >= ceil(N/128)
#define HB 128                // setup/hist blocks

static __device__ __forceinline__ unsigned short f32_to_bf16(float f) {
    union { float f; unsigned u; } v; v.f = f;
    unsigned r = v.u + 0x7fffu + ((v.u >> 16) & 1u);   // round-nearest-even
    return (unsigned short)(r >> 16);
}
static __device__ __forceinline__ float silu(float x) {
    return x / (1.f + __expf(-x));
}
static __device__ __forceinline__ void gload_lds16(const void* gp, void* lp) {
    __builtin_amdgcn_global_load_lds(
        (const __attribute__((address_space(1))) void*)gp,
        (__attribute__((address_space(3))) void*)lp, 16, 0, 0);
}

// ---------- K0: setup = bucket hist partials + weight convert + out zero ----------
__global__ __launch_bounds__(256) void setup_hist_kernel(
        const int* __restrict__ src, int* __restrict__ bpart,
        const float* __restrict__ Wup, const float* __restrict__ Wd,
        unsigned short* __restrict__ Wbf, float* __restrict__ out,
        int E, int nbkt, int outn) {
    __shared__ int h[MAXBKT];
    for (int b = threadIdx.x; b < nbkt; b += 256) h[b] = 0;
    __syncthreads();
    int gtid = blockIdx.x * blockDim.x + threadIdx.x;
    int stride = gridDim.x * blockDim.x;
    for (int e = gtid; e < E; e += stride)
        atomicAdd(&h[src[e] >> BSH], 1);
    for (int j = gtid; j < outn; j += stride) out[j] = 0.f;
    const int n1 = OUT * EMB, n2 = NDENSE * OUT * OUT;
    for (int j = gtid; j < n1 + n2; j += stride)
        Wbf[j] = f32_to_bf16(j < n1 ? Wup[j] : Wd[j - n1]);
    __syncthreads();
    int* row = bpart + (size_t)blockIdx.x * MAXBKT;
    for (int b = threadIdx.x; b < nbkt; b += 256) row[b] = h[b];
}

// ---------- K1: sum partials + scan ----------
__global__ __launch_bounds__(512) void bscan_kernel(
        const int* __restrict__ bpart, int* __restrict__ bbase,
        int* __restrict__ gcursor, int nbkt, int E) {
    __shared__ int s[MAXBKT];
    int t = threadIdx.x;
    int v = 0;
    if (t < nbkt) {
#pragma unroll 8
        for (int k = 0; k < HB; ++k) v += bpart[(size_t)k * MAXBKT + t];
    }
    s[t] = v;
    __syncthreads();
    for (int d = 1; d < MAXBKT; d <<= 1) {
        int x = (t >= d) ? s[t - d] : 0;
        __syncthreads();
        s[t] += x;
        __syncthreads();
    }
    if (t < nbkt) {
        int ex = s[t] - v;
        bbase[t] = ex;
        gcursor[t] = ex;
    }
    if (t == 0) bbase[nbkt] = E;
}

// ---------- K2: scatter edges into bucket-grouped packed pairs ----------
// pair = (e << BSH) | (src & 127)  — single int, halves pair traffic
__global__ __launch_bounds__(256) void bscatter_kernel(
        const int* __restrict__ src, int* __restrict__ gcursor,
        int* __restrict__ pairs, int E, int nbkt) {
    __shared__ int h[MAXBKT];
    __shared__ int base[MAXBKT];
    for (int b = threadIdx.x; b < nbkt; b += 256) h[b] = 0;
    __syncthreads();
    const int per = (E + gridDim.x - 1) / gridDim.x;
    const int e0 = blockIdx.x * per;
    const int e1 = min(e0 + per, E);
    for (int e = e0 + threadIdx.x; e < e1; e += 256)
        atomicAdd(&h[src[e] >> BSH], 1);
    __syncthreads();
    for (int b = threadIdx.x; b < nbkt; b += 256)
        base[b] = h[b] ? atomicAdd(&gcursor[b], h[b]) : 0;
    __syncthreads();
    for (int e = e0 + threadIdx.x; e < e1; e += 256) {
        int s = src[e];
        int pos = atomicAdd(&base[s >> BSH], 1);
        pairs[pos] = (e << BSH) | (s & ((1 << BSH) - 1));
    }
}

// ---------- K3: per-bucket local CSR (counting sort in LDS) ----------
__global__ __launch_bounds__(256) void local_csr_kernel(
        const int* __restrict__ pairs, const int* __restrict__ bbase,
        int* __restrict__ offsets, int* __restrict__ perm, int N, int E, int nbkt) {
    __shared__ int cnt[128], exc[128], cur[128];
    const int b = blockIdx.x;
    const int t = threadIdx.x;
    const int n0 = b << BSH;
    const int nn = min(128, N - n0);
    const int p0 = bbase[b], p1 = bbase[b + 1];
    if (t < 128) cnt[t] = 0;
    __syncthreads();
    for (int i = p0 + t; i < p1; i += 256)
        atomicAdd(&cnt[pairs[i] & 127], 1);
    __syncthreads();
    if (t < 128) exc[t] = cnt[t];
    __syncthreads();
    for (int d = 1; d < 128; d <<= 1) {
        int x = (t >= d && t < 128) ? exc[t - d] : 0;
        __syncthreads();
        if (t < 128) exc[t] += x;
        __syncthreads();
    }
    if (t < 128) {
        int ex = exc[t] - cnt[t];
        cur[t] = ex;
        if (t < nn) offsets[n0 + t] = p0 + ex;
    }
    if (b == 0 && t == 0) offsets[N] = E;
    __syncthreads();
    for (int i = p0 + t; i < p1; i += 256) {
        int pr = pairs[i];
        int pos = p0 + atomicAdd(&cur[pr & 127], 1);
        perm[pos] = pr >> BSH;
    }
}

// ---------- edge transform + per-node gather-sum v4 (R15 exact) ----------
__global__ __launch_bounds__(256) void edge_accum_kernel(
        const float* __restrict__ m, const float* __restrict__ rbf,
        const int* __restrict__ perm, const int* __restrict__ offsets,
        const float* __restrict__ W_rbf, uint2* __restrict__ t_pack, int N) {
    const int lane = threadIdx.x & 63;
    const int h = lane >> 5;
    const int c = lane & 31;
    const int gw = blockIdx.x * (blockDim.x >> 6) + (threadIdx.x >> 6);
    const int nwaves = gridDim.x * (blockDim.x >> 6);

    float wk[4][6];
#pragma unroll
    for (int k = 0; k < 4; ++k)
#pragma unroll
        for (int j = 0; j < 6; ++j) wk[k][j] = W_rbf[(4 * c + k) * NRAD + j];

    for (int node = gw; node < N; node += nwaves) {
        const int beg = offsets[node], end = offsets[node + 1];
        float a0 = 0.f, a1 = 0.f, a2 = 0.f, a3 = 0.f;
        int pe = 0;
        if (beg < end) {
            int pi = beg + (lane & 31); if (pi > end - 1) pi = end - 1;
            pe = perm[pi];
        }
        for (int cb = beg; cb < end; cb += 32) {
            int pe_next = 0;
            if (cb + 32 < end) {
                int pi = cb + 32 + (lane & 31); if (pi > end - 1) pi = end - 1;
                pe_next = perm[pi];
            }
#pragma unroll
            for (int p = 0; p < 16; ++p) {
                int e = __shfl(pe, 2 * p + h);
                const float2* rp = (const float2*)(rbf + (size_t)e * NRAD);
                float2 r0 = rp[0], r1 = rp[1], r2 = rp[2];
                float4 mv = *(const float4*)(m + (size_t)e * EMB + 4 * c);
                float g = (cb + 2 * p + h < end) ? 1.f : 0.f;
                float p0 = (wk[0][0]*r0.x + wk[0][1]*r0.y + wk[0][2]*r1.x
                          + wk[0][3]*r1.y + wk[0][4]*r2.x + wk[0][5]*r2.y) * g;
                float p1 = (wk[1][0]*r0.x + wk[1][1]*r0.y + wk[1][2]*r1.x
                          + wk[1][3]*r1.y + wk[1][4]*r2.x + wk[1][5]*r2.y) * g;
                float p2 = (wk[2][0]*r0.x + wk[2][1]*r0.y + wk[2][2]*r1.x
                          + wk[2][3]*r1.y + wk[2][4]*r2.x + wk[2][5]*r2.y) * g;
                float p3 = (wk[3][0]*r0.x + wk[3][1]*r0.y + wk[3][2]*r1.x
                          + wk[3][3]*r1.y + wk[3][4]*r2.x + wk[3][5]*r2.y) * g;
                a0 = fmaf(mv.x, p0, a0);
                a1 = fmaf(mv.y, p1, a1);
                a2 = fmaf(mv.z, p2, a2);
                a3 = fmaf(mv.w, p3, a3);
            }
            pe = pe_next;
        }
        a0 += __shfl_xor(a0, 32);
        a1 += __shfl_xor(a1, 32);
        a2 += __shfl_xor(a2, 32);
        a3 += __shfl_xor(a3, 32);
        if (h == 0) {
            uint2 pk;
            pk.x = (unsigned)f32_to_bf16(a0) | ((unsigned)f32_to_bf16(a1) << 16);
            pk.y = (unsigned)f32_to_bf16(a2) | ((unsigned)f32_to_bf16(a3) << 16);
            t_pack[(size_t)node * 32 + c] = pk;
        }
    }
}

// ---------- fused MLP v3 (R15 exact): 64KB LDS, 64-K chunks, swizzled Wbuf ----------
__global__ __launch_bounds__(256) void fused_mlp2_kernel(
        const unsigned short* __restrict__ A0,    // [M,128] bf16
        const unsigned short* __restrict__ Wup,   // [256,128] bf16
        const unsigned short* __restrict__ Wd,    // [3,256,256] bf16
        const float* __restrict__ bd,             // [3,256]
        const int* __restrict__ gids,             // [M] sorted
        float* __restrict__ out, int M) {
    __shared__ char Abuf[32768];
    __shared__ char Wbuf[32768];
    const int t    = threadIdx.x;
    const int w    = t >> 6;
    const int lane = t & 63;
    const int r    = lane & 15;
    const int g    = lane >> 4;
    const int row0 = blockIdx.x * 64;

    f32x4 acc[4][4];

    // ---- stage A0: 64 rows x 256B (pre-swizzled source, linear dest) ----
#pragma unroll
    for (int it = 0; it < 4; ++it) {
        int unit = it * 256 + t;
        int row  = unit >> 4;
        int seg  = unit & 15;
        int csrc = (seg * 16) ^ ((row & 7) << 4);
        int ga = row0 + row; if (ga >= M) ga = M - 1;
        gload_lds16((const char*)A0 + (size_t)ga * 256 + csrc, Abuf + unit * 16);
    }

    // ---- layer 0: K=128 ----
#pragma unroll
    for (int i = 0; i < 4; ++i)
#pragma unroll
        for (int j = 0; j < 4; ++j) acc[i][j] = (f32x4){0.f, 0.f, 0.f, 0.f};
#pragma unroll
    for (int kci = 0; kci < 2; ++kci) {
        const int kc = kci * 64;
        if (kci) __syncthreads();
#pragma unroll
        for (int it = 0; it < 8; ++it) {
            int unit = it * 256 + t;
            int wrow = unit >> 3;
            int seg  = unit & 7;
            int csrc = (seg * 16) ^ ((wrow & 7) << 4);
            gload_lds16((const char*)Wup + (size_t)wrow * 256 + kc * 2 + csrc,
                        Wbuf + unit * 16);
        }
        asm volatile("s_waitcnt vmcnt(0)" ::: "memory");
        __syncthreads();
#pragma unroll
        for (int ks = 0; ks < 2; ++ks) {
            short8 af[4], bf[4];
#pragma unroll
            for (int mi = 0; mi < 4; ++mi) {
                int row = mi * 16 + r;
                int off = kc * 2 + ks * 64 + g * 16;
                af[mi] = *(const short8*)(Abuf + row * 256 + (off ^ ((row & 7) << 4)));
            }
#pragma unroll
            for (int nj = 0; nj < 4; ++nj) {
                int col = w * 64 + nj * 16 + r;
                bf[nj] = *(const short8*)(Wbuf + col * 128
                          + ((ks * 64 + g * 16) ^ ((col & 7) << 4)));
            }
#pragma unroll
            for (int mi = 0; mi < 4; ++mi)
#pragma unroll
                for (int nj = 0; nj < 4; ++nj)
                    acc[mi][nj] = __builtin_amdgcn_mfma_f32_16x16x32_bf16(
                        af[mi], bf[nj], acc[mi][nj], 0, 0, 0);
        }
    }
    __syncthreads();
#pragma unroll
    for (int mi = 0; mi < 4; ++mi)
#pragma unroll
        for (int nj = 0; nj < 4; ++nj)
#pragma unroll
            for (int q = 0; q < 4; ++q) {
                int row = mi * 16 + g * 4 + q;
                int col = w * 64 + nj * 16 + r;
                *(unsigned short*)(Abuf + row * 512 + ((col * 2) ^ ((row & 7) << 4)))
                    = f32_to_bf16(acc[mi][nj][q]);
            }
    __syncthreads();

    // ---- layers 1..3: K=256 ----
    for (int ell = 0; ell < NDENSE; ++ell) {
        const unsigned short* Wl = Wd + (size_t)ell * OUT * OUT;
        const float* bias = bd + ell * OUT;
#pragma unroll
        for (int i = 0; i < 4; ++i)
#pragma unroll
            for (int j = 0; j < 4; ++j) acc[i][j] = (f32x4){0.f, 0.f, 0.f, 0.f};
#pragma unroll
        for (int kci = 0; kci < 4; ++kci) {
            const int kc = kci * 64;
            __syncthreads();
#pragma unroll
            for (int it = 0; it < 8; ++it) {
                int unit = it * 256 + t;
                int wrow = unit >> 3;
                int seg  = unit & 7;
                int csrc = (seg * 16) ^ ((wrow & 7) << 4);
                gload_lds16((const char*)Wl + (size_t)wrow * 512 + kc * 2 + csrc,
                            Wbuf + unit * 16);
            }
            asm volatile("s_waitcnt vmcnt(0)" ::: "memory");
            __syncthreads();
#pragma unroll
            for (int ks = 0; ks < 2; ++ks) {
                short8 af[4], bf[4];
#pragma unroll
                for (int mi = 0; mi < 4; ++mi) {
                    int row = mi * 16 + r;
                    int off = kc * 2 + ks * 64 + g * 16;
                    af[mi] = *(const short8*)(Abuf + row * 512 + (off ^ ((row & 7) << 4)));
                }
#pragma unroll
                for (int nj = 0; nj < 4; ++nj) {
                    int col = w * 64 + nj * 16 + r;
                    bf[nj] = *(const short8*)(Wbuf + col * 128
                              + ((ks * 64 + g * 16) ^ ((col & 7) << 4)));
                }
#pragma unroll
                for (int mi = 0; mi < 4; ++mi)
#pragma unroll
                    for (int nj = 0; nj < 4; ++nj)
                        acc[mi][nj] = __builtin_amdgcn_mfma_f32_16x16x32_bf16(
                            af[mi], bf[nj], acc[mi][nj], 0, 0, 0);
            }
        }
        __syncthreads();
        if (ell < NDENSE - 1) {
#pragma unroll
            for (int mi = 0; mi < 4; ++mi)
#pragma unroll
                for (int nj = 0; nj < 4; ++nj) {
                    int col = w * 64 + nj * 16 + r;
                    float b = bias[col];
#pragma unroll
                    for (int q = 0; q < 4; ++q) {
                        int row = mi * 16 + g * 4 + q;
                        *(unsigned short*)(Abuf + row * 512
                            + ((col * 2) ^ ((row & 7) << 4)))
                            = f32_to_bf16(silu(acc[mi][nj][q] + b));
                    }
                }
            __syncthreads();
        } else {
            // ---- final layer: silu + per-graph reduce, atomicAdd into out ----
            bool uni = (row0 + 63 < M) && (gids[row0] == gids[row0 + 63]);
            if (uni) {
                int gph = gids[row0];
                float* og = out + (size_t)gph * OUT;
#pragma unroll
                for (int nj = 0; nj < 4; ++nj) {
                    int gcol = w * 64 + nj * 16 + r;
                    float b = bias[gcol];
                    float s = 0.f;
#pragma unroll
                    for (int mi = 0; mi < 4; ++mi)
#pragma unroll
                        for (int q = 0; q < 4; ++q)
                            s += silu(acc[mi][nj][q] + b);
                    s += __shfl_xor(s, 16);
                    s += __shfl_xor(s, 32);
                    if (g == 0) atomicAdd(&og[gcol], s);
                }
            } else {
#pragma unroll
                for (int nj = 0; nj < 4; ++nj) {
                    int gcol = w * 64 + nj * 16 + r;
                    float b = bias[gcol];
#pragma unroll
                    for (int mi = 0; mi < 4; ++mi)
#pragma unroll
                        for (int q = 0; q < 4; ++q) {
                            int grow = row0 + mi * 16 + g * 4 + q;
                            if (grow < M)
                                atomicAdd(&out[(size_t)gids[grow] * OUT + gcol],
                                          silu(acc[mi][nj][q] + b));
                        }
                }
            }
        }
    }
}

// ---------- host ----------
extern "C" void kernel_launch(void* const* d_in, const int* in_sizes, int n_in,
                              void* d_out, int out_size, void* d_ws, size_t ws_size,
                              hipStream_t stream) {
    const float* m         = (const float*)d_in[0];
    const float* rbf       = (const float*)d_in[1];
    const int*   src       = (const int*)d_in[2];
    const int*   gids      = (const int*)d_in[3];
    const float* W_rbf     = (const float*)d_in[4];
    const float* W_up      = (const float*)d_in[5];
    const float* W_dense   = (const float*)d_in[6];
    const float* b_dense   = (const float*)d_in[7];
    float* out = (float*)d_out;

    const int E = in_sizes[2];
    const int N = in_sizes[3];
    const int nbkt = (N + 127) >> BSH;     // 391 for N=50000

    size_t off = 0;
    auto alloc = [&](size_t bytes) -> void* {
        void* p = (char*)d_ws + off;
        off += (bytes + 255) & ~(size_t)255;
        return p;
    };
    int* bpart   = (int*)alloc((size_t)HB * MAXBKT * 4);
    int* bbase   = (int*)alloc((size_t)(MAXBKT + 1) * 4);
    int* gcursor = (int*)alloc((size_t)MAXBKT * 4);
    int* offsets = (int*)alloc(((size_t)N + 1) * 4);
    int* pairs   = (int*)alloc((size_t)E * 4);
    int* perm    = (int*)alloc((size_t)E * 4);
    unsigned short* t_bf = (unsigned short*)alloc((size_t)N * EMB * 2);
    unsigned short* Wbf  = (unsigned short*)alloc((size_t)(OUT * EMB + NDENSE * OUT * OUT) * 2);
    unsigned short* Wup_bf = Wbf;
    unsigned short* Wd_bf  = Wbf + OUT * EMB;

    // K0: setup = hist partials + weight convert + out zero (merged)
    setup_hist_kernel<<<HB, 256, 0, stream>>>(src, bpart, W_up, W_dense, Wbf,
                                              out, E, nbkt, out_size);
    // K1..K3: scan, scatter, local CSR
    bscan_kernel<<<1, MAXBKT, 0, stream>>>(bpart, bbase, gcursor, nbkt, E);
    bscatter_kernel<<<512, 256, 0, stream>>>(src, gcursor, pairs, E, nbkt);
    local_csr_kernel<<<nbkt, 256, 0, stream>>>(pairs, bbase, offsets, perm, N, E, nbkt);

    // edge transform + node gather v4
    edge_accum_kernel<<<2048, 256, 0, stream>>>(m, rbf, perm, offsets, W_rbf,
                                                (uint2*)t_bf, N);

    // fused MLP + per-graph readout (atomic into zeroed out)
    fused_mlp2_kernel<<<(N + 63) / 64, 256, 0, stream>>>(t_bf, Wup_bf, Wd_bf,
                                                         b_dense, gids, out, N);
}

// Round 18
// 407.939 us; speedup vs baseline: 1.1344x; 1.0395x over previous
//
#include <hip/hip_runtime.h>
#include <hip/hip_bf16.h>

// ---------- types ----------
typedef __attribute__((ext_vector_type(8))) short short8;
typedef __attribute__((ext_vector_type(4))) float f32x4;

#define EMB 128
#define OUT 256
#define NRAD 6
#define NDENSE 3
#define BSH 7                 // bucket shift: 128 nodes per bucket
#define MAXBKT 512            // >= ceil(N/128)
#define HB 128                // setup/hist blocks

static __device__ __forceinline__ unsigned short f32_to_bf16(float f) {
    union { float f; unsigned u; } v; v.f = f;
    unsigned r = v.u + 0x7fffu + ((v.u >> 16) & 1u);   // round-nearest-even
    return (unsigned short)(r >> 16);
}
static __device__ __forceinline__ float silu(float x) {
    return x / (1.f + __expf(-x));
}
static __device__ __forceinline__ void gload_lds16(const void* gp, void* lp) {
    __builtin_amdgcn_global_load_lds(
        (const __attribute__((address_space(1))) void*)gp,
        (__attribute__((address_space(3))) void*)lp, 16, 0, 0);
}

// ---------- K0: setup = bucket hist partials + weight convert + out zero ----------
__global__ __launch_bounds__(256) void setup_hist_kernel(
        const int* __restrict__ src, int* __restrict__ bpart,
        const float* __restrict__ Wup, const float* __restrict__ Wd,
        unsigned short* __restrict__ Wbf, float* __restrict__ out,
        int E, int nbkt, int outn) {
    __shared__ int h[MAXBKT];
    for (int b = threadIdx.x; b < nbkt; b += 256) h[b] = 0;
    __syncthreads();
    int gtid = blockIdx.x * blockDim.x + threadIdx.x;
    int stride = gridDim.x * blockDim.x;
    for (int e = gtid; e < E; e += stride)
        atomicAdd(&h[src[e] >> BSH], 1);
    for (int j = gtid; j < outn; j += stride) out[j] = 0.f;
    const int n1 = OUT * EMB, n2 = NDENSE * OUT * OUT;
    for (int j = gtid; j < n1 + n2; j += stride)
        Wbf[j] = f32_to_bf16(j < n1 ? Wup[j] : Wd[j - n1]);
    __syncthreads();
    int* row = bpart + (size_t)blockIdx.x * MAXBKT;
    for (int b = threadIdx.x; b < nbkt; b += 256) row[b] = h[b];
}

// ---------- K1: sum partials + scan ----------
__global__ __launch_bounds__(512) void bscan_kernel(
        const int* __restrict__ bpart, int* __restrict__ bbase,
        int* __restrict__ gcursor, int nbkt, int E) {
    __shared__ int s[MAXBKT];
    int t = threadIdx.x;
    int v = 0;
    if (t < nbkt) {
#pragma unroll 8
        for (int k = 0; k < HB; ++k) v += bpart[(size_t)k * MAXBKT + t];
    }
    s[t] = v;
    __syncthreads();
    for (int d = 1; d < MAXBKT; d <<= 1) {
        int x = (t >= d) ? s[t - d] : 0;
        __syncthreads();
        s[t] += x;
        __syncthreads();
    }
    if (t < nbkt) {
        int ex = s[t] - v;
        bbase[t] = ex;
        gcursor[t] = ex;
    }
    if (t == 0) bbase[nbkt] = E;
}

// ---------- K2: scatter edges into bucket-grouped packed pairs ----------
__global__ __launch_bounds__(256) void bscatter_kernel(
        const int* __restrict__ src, int* __restrict__ gcursor,
        int* __restrict__ pairs, int E, int nbkt) {
    __shared__ int h[MAXBKT];
    __shared__ int base[MAXBKT];
    for (int b = threadIdx.x; b < nbkt; b += 256) h[b] = 0;
    __syncthreads();
    const int per = (E + gridDim.x - 1) / gridDim.x;
    const int e0 = blockIdx.x * per;
    const int e1 = min(e0 + per, E);
    for (int e = e0 + threadIdx.x; e < e1; e += 256)
        atomicAdd(&h[src[e] >> BSH], 1);
    __syncthreads();
    for (int b = threadIdx.x; b < nbkt; b += 256)
        base[b] = h[b] ? atomicAdd(&gcursor[b], h[b]) : 0;
    __syncthreads();
    for (int e = e0 + threadIdx.x; e < e1; e += 256) {
        int s = src[e];
        int pos = atomicAdd(&base[s >> BSH], 1);
        pairs[pos] = (e << BSH) | (s & ((1 << BSH) - 1));
    }
}

// ---------- K3: per-bucket local CSR (counting sort in LDS) ----------
__global__ __launch_bounds__(256) void local_csr_kernel(
        const int* __restrict__ pairs, const int* __restrict__ bbase,
        int* __restrict__ offsets, int* __restrict__ perm, int N, int E, int nbkt) {
    __shared__ int cnt[128], exc[128], cur[128];
    const int b = blockIdx.x;
    const int t = threadIdx.x;
    const int n0 = b << BSH;
    const int nn = min(128, N - n0);
    const int p0 = bbase[b], p1 = bbase[b + 1];
    if (t < 128) cnt[t] = 0;
    __syncthreads();
    for (int i = p0 + t; i < p1; i += 256)
        atomicAdd(&cnt[pairs[i] & 127], 1);
    __syncthreads();
    if (t < 128) exc[t] = cnt[t];
    __syncthreads();
    for (int d = 1; d < 128; d <<= 1) {
        int x = (t >= d && t < 128) ? exc[t - d] : 0;
        __syncthreads();
        if (t < 128) exc[t] += x;
        __syncthreads();
    }
    if (t < 128) {
        int ex = exc[t] - cnt[t];
        cur[t] = ex;
        if (t < nn) offsets[n0 + t] = p0 + ex;
    }
    if (b == 0 && t == 0) offsets[N] = E;
    __syncthreads();
    for (int i = p0 + t; i < p1; i += 256) {
        int pr = pairs[i];
        int pos = p0 + atomicAdd(&cur[pr & 127], 1);
        perm[pos] = pr >> BSH;
    }
}

// ---------- edge transform + per-node gather-sum v5 (dynamic tail trip count) ----------
// 32 lanes per edge row; 32 perm ids staged in lane&31. The p-loop runs only
// np = ceil(rem/2) iterations (dynamic bound, unroll-4 batches) instead of a
// fixed 16 — cuts ~45% wasted clamped-duplicate issue slots on Poisson(32)
// degree tails. Loads remain unconditional within batches (R13 lesson).
__global__ __launch_bounds__(256) void edge_accum_kernel(
        const float* __restrict__ m, const float* __restrict__ rbf,
        const int* __restrict__ perm, const int* __restrict__ offsets,
        const float* __restrict__ W_rbf, uint2* __restrict__ t_pack, int N) {
    const int lane = threadIdx.x & 63;
    const int h = lane >> 5;
    const int c = lane & 31;
    const int gw = blockIdx.x * (blockDim.x >> 6) + (threadIdx.x >> 6);
    const int nwaves = gridDim.x * (blockDim.x >> 6);

    float wk[4][6];
#pragma unroll
    for (int k = 0; k < 4; ++k)
#pragma unroll
        for (int j = 0; j < 6; ++j) wk[k][j] = W_rbf[(4 * c + k) * NRAD + j];

    for (int node = gw; node < N; node += nwaves) {
        const int beg = offsets[node], end = offsets[node + 1];
        float a0 = 0.f, a1 = 0.f, a2 = 0.f, a3 = 0.f;
        int pe = 0;
        if (beg < end) {
            int pi = beg + (lane & 31); if (pi > end - 1) pi = end - 1;
            pe = perm[pi];
        }
        for (int cb = beg; cb < end; cb += 32) {
            int pe_next = 0;
            if (cb + 32 < end) {
                int pi = cb + 32 + (lane & 31); if (pi > end - 1) pi = end - 1;
                pe_next = perm[pi];
            }
            const int rem = end - cb;
            const int np = (rem >= 32) ? 16 : ((rem + 1) >> 1);
#pragma unroll 4
            for (int p = 0; p < np; ++p) {
                int e = __shfl(pe, 2 * p + h);
                const float2* rp = (const float2*)(rbf + (size_t)e * NRAD);
                float2 r0 = rp[0], r1 = rp[1], r2 = rp[2];
                float4 mv = *(const float4*)(m + (size_t)e * EMB + 4 * c);
                float g = (2 * p + h < rem) ? 1.f : 0.f;
                float p0 = (wk[0][0]*r0.x + wk[0][1]*r0.y + wk[0][2]*r1.x
                          + wk[0][3]*r1.y + wk[0][4]*r2.x + wk[0][5]*r2.y) * g;
                float p1 = (wk[1][0]*r0.x + wk[1][1]*r0.y + wk[1][2]*r1.x
                          + wk[1][3]*r1.y + wk[1][4]*r2.x + wk[1][5]*r2.y) * g;
                float p2 = (wk[2][0]*r0.x + wk[2][1]*r0.y + wk[2][2]*r1.x
                          + wk[2][3]*r1.y + wk[2][4]*r2.x + wk[2][5]*r2.y) * g;
                float p3 = (wk[3][0]*r0.x + wk[3][1]*r0.y + wk[3][2]*r1.x
                          + wk[3][3]*r1.y + wk[3][4]*r2.x + wk[3][5]*r2.y) * g;
                a0 = fmaf(mv.x, p0, a0);
                a1 = fmaf(mv.y, p1, a1);
                a2 = fmaf(mv.z, p2, a2);
                a3 = fmaf(mv.w, p3, a3);
            }
            pe = pe_next;
        }
        a0 += __shfl_xor(a0, 32);
        a1 += __shfl_xor(a1, 32);
        a2 += __shfl_xor(a2, 32);
        a3 += __shfl_xor(a3, 32);
        if (h == 0) {
            uint2 pk;
            pk.x = (unsigned)f32_to_bf16(a0) | ((unsigned)f32_to_bf16(a1) << 16);
            pk.y = (unsigned)f32_to_bf16(a2) | ((unsigned)f32_to_bf16(a3) << 16);
            t_pack[(size_t)node * 32 + c] = pk;
        }
    }
}

// ---------- fused MLP v3 (R15/R17 exact) ----------
__global__ __launch_bounds__(256) void fused_mlp2_kernel(
        const unsigned short* __restrict__ A0,    // [M,128] bf16
        const unsigned short* __restrict__ Wup,   // [256,128] bf16
        const unsigned short* __restrict__ Wd,    // [3,256,256] bf16
        const float* __restrict__ bd,             // [3,256]
        const int* __restrict__ gids,             // [M] sorted
        float* __restrict__ out, int M) {
    __shared__ char Abuf[32768];
    __shared__ char Wbuf[32768];
    const int t    = threadIdx.x;
    const int w    = t >> 6;
    const int lane = t & 63;
    const int r    = lane & 15;
    const int g    = lane >> 4;
    const int row0 = blockIdx.x * 64;

    f32x4 acc[4][4];

#pragma unroll
    for (int it = 0; it < 4; ++it) {
        int unit = it * 256 + t;
        int row  = unit >> 4;
        int seg  = unit & 15;
        int csrc = (seg * 16) ^ ((row & 7) << 4);
        int ga = row0 + row; if (ga >= M) ga = M - 1;
        gload_lds16((const char*)A0 + (size_t)ga * 256 + csrc, Abuf + unit * 16);
    }

    // ---- layer 0: K=128 ----
#pragma unroll
    for (int i = 0; i < 4; ++i)
#pragma unroll
        for (int j = 0; j < 4; ++j) acc[i][j] = (f32x4){0.f, 0.f, 0.f, 0.f};
#pragma unroll
    for (int kci = 0; kci < 2; ++kci) {
        const int kc = kci * 64;
        if (kci) __syncthreads();
#pragma unroll
        for (int it = 0; it < 8; ++it) {
            int unit = it * 256 + t;
            int wrow = unit >> 3;
            int seg  = unit & 7;
            int csrc = (seg * 16) ^ ((wrow & 7) << 4);
            gload_lds16((const char*)Wup + (size_t)wrow * 256 + kc * 2 + csrc,
                        Wbuf + unit * 16);
        }
        asm volatile("s_waitcnt vmcnt(0)" ::: "memory");
        __syncthreads();
#pragma unroll
        for (int ks = 0; ks < 2; ++ks) {
            short8 af[4], bf[4];
#pragma unroll
            for (int mi = 0; mi < 4; ++mi) {
                int row = mi * 16 + r;
                int off = kc * 2 + ks * 64 + g * 16;
                af[mi] = *(const short8*)(Abuf + row * 256 + (off ^ ((row & 7) << 4)));
            }
#pragma unroll
            for (int nj = 0; nj < 4; ++nj) {
                int col = w * 64 + nj * 16 + r;
                bf[nj] = *(const short8*)(Wbuf + col * 128
                          + ((ks * 64 + g * 16) ^ ((col & 7) << 4)));
            }
#pragma unroll
            for (int mi = 0; mi < 4; ++mi)
#pragma unroll
                for (int nj = 0; nj < 4; ++nj)
                    acc[mi][nj] = __builtin_amdgcn_mfma_f32_16x16x32_bf16(
                        af[mi], bf[nj], acc[mi][nj], 0, 0, 0);
        }
    }
    __syncthreads();
#pragma unroll
    for (int mi = 0; mi < 4; ++mi)
#pragma unroll
        for (int nj = 0; nj < 4; ++nj)
#pragma unroll
            for (int q = 0; q < 4; ++q) {
                int row = mi * 16 + g * 4 + q;
                int col = w * 64 + nj * 16 + r;
                *(unsigned short*)(Abuf + row * 512 + ((col * 2) ^ ((row & 7) << 4)))
                    = f32_to_bf16(acc[mi][nj][q]);
            }
    __syncthreads();

    // ---- layers 1..3: K=256 ----
    for (int ell = 0; ell < NDENSE; ++ell) {
        const unsigned short* Wl = Wd + (size_t)ell * OUT * OUT;
        const float* bias = bd + ell * OUT;
#pragma unroll
        for (int i = 0; i < 4; ++i)
#pragma unroll
            for (int j = 0; j < 4; ++j) acc[i][j] = (f32x4){0.f, 0.f, 0.f, 0.f};
#pragma unroll
        for (int kci = 0; kci < 4; ++kci) {
            const int kc = kci * 64;
            __syncthreads();
#pragma unroll
            for (int it = 0; it < 8; ++it) {
                int unit = it * 256 + t;
                int wrow = unit >> 3;
                int seg  = unit & 7;
                int csrc = (seg * 16) ^ ((wrow & 7) << 4);
                gload_lds16((const char*)Wl + (size_t)wrow * 512 + kc * 2 + csrc,
                            Wbuf + unit * 16);
            }
            asm volatile("s_waitcnt vmcnt(0)" ::: "memory");
            __syncthreads();
#pragma unroll
            for (int ks = 0; ks < 2; ++ks) {
                short8 af[4], bf[4];
#pragma unroll
                for (int mi = 0; mi < 4; ++mi) {
                    int row = mi * 16 + r;
                    int off = kc * 2 + ks * 64 + g * 16;
                    af[mi] = *(const short8*)(Abuf + row * 512 + (off ^ ((row & 7) << 4)));
                }
#pragma unroll
                for (int nj = 0; nj < 4; ++nj) {
                    int col = w * 64 + nj * 16 + r;
                    bf[nj] = *(const short8*)(Wbuf + col * 128
                              + ((ks * 64 + g * 16) ^ ((col & 7) << 4)));
                }
#pragma unroll
                for (int mi = 0; mi < 4; ++mi)
#pragma unroll
                    for (int nj = 0; nj < 4; ++nj)
                        acc[mi][nj] = __builtin_amdgcn_mfma_f32_16x16x32_bf16(
                            af[mi], bf[nj], acc[mi][nj], 0, 0, 0);
            }
        }
        __syncthreads();
        if (ell < NDENSE - 1) {
#pragma unroll
            for (int mi = 0; mi < 4; ++mi)
#pragma unroll
                for (int nj = 0; nj < 4; ++nj) {
                    int col = w * 64 + nj * 16 + r;
                    float b = bias[col];
#pragma unroll
                    for (int q = 0; q < 4; ++q) {
                        int row = mi * 16 + g * 4 + q;
                        *(unsigned short*)(Abuf + row * 512
                            + ((col * 2) ^ ((row & 7) << 4)))
                            = f32_to_bf16(silu(acc[mi][nj][q] + b));
                    }
                }
            __syncthreads();
        } else {
            bool uni = (row0 + 63 < M) && (gids[row0] == gids[row0 + 63]);
            if (uni) {
                int gph = gids[row0];
                float* og = out + (size_t)gph * OUT;
#pragma unroll
                for (int nj = 0; nj < 4; ++nj) {
                    int gcol = w * 64 + nj * 16 + r;
                    float b = bias[gcol];
                    float s = 0.f;
#pragma unroll
                    for (int mi = 0; mi < 4; ++mi)
#pragma unroll
                        for (int q = 0; q < 4; ++q)
                            s += silu(acc[mi][nj][q] + b);
                    s += __shfl_xor(s, 16);
                    s += __shfl_xor(s, 32);
                    if (g == 0) atomicAdd(&og[gcol], s);
                }
            } else {
#pragma unroll
                for (int nj = 0; nj < 4; ++nj) {
                    int gcol = w * 64 + nj * 16 + r;
                    float b = bias[gcol];
#pragma unroll
                    for (int mi = 0; mi < 4; ++mi)
#pragma unroll
                        for (int q = 0; q < 4; ++q) {
                            int grow = row0 + mi * 16 + g * 4 + q;
                            if (grow < M)
                                atomicAdd(&out[(size_t)gids[grow] * OUT + gcol],
                                          silu(acc[mi][nj][q] + b));
                        }
                }
            }
        }
    }
}

// ---------- host ----------
extern "C" void kernel_launch(void* const* d_in, const int* in_sizes, int n_in,
                              void* d_out, int out_size, void* d_ws, size_t ws_size,
                              hipStream_t stream) {
    const float* m         = (const float*)d_in[0];
    const float* rbf       = (const float*)d_in[1];
    const int*   src       = (const int*)d_in[2];
    const int*   gids      = (const int*)d_in[3];
    const float* W_rbf     = (const float*)d_in[4];
    const float* W_up      = (const float*)d_in[5];
    const float* W_dense   = (const float*)d_in[6];
    const float* b_dense   = (const float*)d_in[7];
    float* out = (float*)d_out;

    const int E = in_sizes[2];
    const int N = in_sizes[3];
    const int nbkt = (N + 127) >> BSH;     // 391 for N=50000

    size_t off = 0;
    auto alloc = [&](size_t bytes) -> void* {
        void* p = (char*)d_ws + off;
        off += (bytes + 255) & ~(size_t)255;
        return p;
    };
    int* bpart   = (int*)alloc((size_t)HB * MAXBKT * 4);
    int* bbase   = (int*)alloc((size_t)(MAXBKT + 1) * 4);
    int* gcursor = (int*)alloc((size_t)MAXBKT * 4);
    int* offsets = (int*)alloc(((size_t)N + 1) * 4);
    int* pairs   = (int*)alloc((size_t)E * 4);
    int* perm    = (int*)alloc((size_t)E * 4);
    unsigned short* t_bf = (unsigned short*)alloc((size_t)N * EMB * 2);
    unsigned short* Wbf  = (unsigned short*)alloc((size_t)(OUT * EMB + NDENSE * OUT * OUT) * 2);
    unsigned short* Wup_bf = Wbf;
    unsigned short* Wd_bf  = Wbf + OUT * EMB;

    // K0: setup = hist partials + weight convert + out zero (merged)
    setup_hist_kernel<<<HB, 256, 0, stream>>>(src, bpart, W_up, W_dense, Wbf,
                                              out, E, nbkt, out_size);
    // K1..K3: scan, scatter, local CSR
    bscan_kernel<<<1, MAXBKT, 0, stream>>>(bpart, bbase, gcursor, nbkt, E);
    bscatter_kernel<<<512, 256, 0, stream>>>(src, gcursor, pairs, E, nbkt);
    local_csr_kernel<<<nbkt, 256, 0, stream>>>(pairs, bbase, offsets, perm, N, E, nbkt);

    // edge transform + node gather v5 (dynamic tail trip count)
    edge_accum_kernel<<<2048, 256, 0, stream>>>(m, rbf, perm, offsets, W_rbf,
                                                (uint2*)t_bf, N);

    // fused MLP + per-graph readout (atomic into zeroed out)
    fused_mlp2_kernel<<<(N + 63) / 64, 256, 0, stream>>>(t_bf, Wup_bf, Wd_bf,
                                                         b_dense, gids, out, N);
}

// Round 19
// 397.731 us; speedup vs baseline: 1.1635x; 1.0257x over previous
//
#include <hip/hip_runtime.h>
#include <hip/hip_bf16.h>

// ---------- types ----------
typedef __attribute__((ext_vector_type(8))) short short8;
typedef __attribute__((ext_vector_type(4))) float f32x4;

#define EMB 128
#define OUT 256
#define NRAD 6
#define NDENSE 3
#define BSH 7                 // bucket shift: 128 nodes per bucket
#define MAXBKT 512            // >= ceil(N/128)
#define HB 128                // setup/hist blocks

static __device__ __forceinline__ unsigned short f32_to_bf16(float f) {
    union { float f; unsigned u; } v; v.f = f;
    unsigned r = v.u + 0x7fffu + ((v.u >> 16) & 1u);   // round-nearest-even
    return (unsigned short)(r >> 16);
}
static __device__ __forceinline__ float silu(float x) {
    return x / (1.f + __expf(-x));
}
static __device__ __forceinline__ void gload_lds16(const void* gp, void* lp) {
    __builtin_amdgcn_global_load_lds(
        (const __attribute__((address_space(1))) void*)gp,
        (__attribute__((address_space(3))) void*)lp, 16, 0, 0);
}

// ---------- K0: setup = bucket hist partials + weight convert + out zero ----------
__global__ __launch_bounds__(256) void setup_hist_kernel(
        const int* __restrict__ src, int* __restrict__ bpart,
        const float* __restrict__ Wup, const float* __restrict__ Wd,
        unsigned short* __restrict__ Wbf, float* __restrict__ out,
        int E, int nbkt, int outn) {
    __shared__ int h[MAXBKT];
    for (int b = threadIdx.x; b < nbkt; b += 256) h[b] = 0;
    __syncthreads();
    int gtid = blockIdx.x * blockDim.x + threadIdx.x;
    int stride = gridDim.x * blockDim.x;
    for (int e = gtid; e < E; e += stride)
        atomicAdd(&h[src[e] >> BSH], 1);
    for (int j = gtid; j < outn; j += stride) out[j] = 0.f;
    const int n1 = OUT * EMB, n2 = NDENSE * OUT * OUT;
    for (int j = gtid; j < n1 + n2; j += stride)
        Wbf[j] = f32_to_bf16(j < n1 ? Wup[j] : Wd[j - n1]);
    __syncthreads();
    int* row = bpart + (size_t)blockIdx.x * MAXBKT;
    for (int b = threadIdx.x; b < nbkt; b += 256) row[b] = h[b];
}

// ---------- K1: sum partials + scan ----------
__global__ __launch_bounds__(512) void bscan_kernel(
        const int* __restrict__ bpart, int* __restrict__ bbase,
        int* __restrict__ gcursor, int nbkt, int E) {
    __shared__ int s[MAXBKT];
    int t = threadIdx.x;
    int v = 0;
    if (t < nbkt) {
#pragma unroll 8
        for (int k = 0; k < HB; ++k) v += bpart[(size_t)k * MAXBKT + t];
    }
    s[t] = v;
    __syncthreads();
    for (int d = 1; d < MAXBKT; d <<= 1) {
        int x = (t >= d) ? s[t - d] : 0;
        __syncthreads();
        s[t] += x;
        __syncthreads();
    }
    if (t < nbkt) {
        int ex = s[t] - v;
        bbase[t] = ex;
        gcursor[t] = ex;
    }
    if (t == 0) bbase[nbkt] = E;
}

// ---------- K2: scatter edges into bucket-grouped packed pairs ----------
__global__ __launch_bounds__(256) void bscatter_kernel(
        const int* __restrict__ src, int* __restrict__ gcursor,
        int* __restrict__ pairs, int E, int nbkt) {
    __shared__ int h[MAXBKT];
    __shared__ int base[MAXBKT];
    for (int b = threadIdx.x; b < nbkt; b += 256) h[b] = 0;
    __syncthreads();
    const int per = (E + gridDim.x - 1) / gridDim.x;
    const int e0 = blockIdx.x * per;
    const int e1 = min(e0 + per, E);
    for (int e = e0 + threadIdx.x; e < e1; e += 256)
        atomicAdd(&h[src[e] >> BSH], 1);
    __syncthreads();
    for (int b = threadIdx.x; b < nbkt; b += 256)
        base[b] = h[b] ? atomicAdd(&gcursor[b], h[b]) : 0;
    __syncthreads();
    for (int e = e0 + threadIdx.x; e < e1; e += 256) {
        int s = src[e];
        int pos = atomicAdd(&base[s >> BSH], 1);
        pairs[pos] = (e << BSH) | (s & ((1 << BSH) - 1));
    }
}

// ---------- K3: per-bucket local CSR (counting sort in LDS) ----------
__global__ __launch_bounds__(256) void local_csr_kernel(
        const int* __restrict__ pairs, const int* __restrict__ bbase,
        int* __restrict__ offsets, int* __restrict__ perm, int N, int E, int nbkt) {
    __shared__ int cnt[128], exc[128], cur[128];
    const int b = blockIdx.x;
    const int t = threadIdx.x;
    const int n0 = b << BSH;
    const int nn = min(128, N - n0);
    const int p0 = bbase[b], p1 = bbase[b + 1];
    if (t < 128) cnt[t] = 0;
    __syncthreads();
    for (int i = p0 + t; i < p1; i += 256)
        atomicAdd(&cnt[pairs[i] & 127], 1);
    __syncthreads();
    if (t < 128) exc[t] = cnt[t];
    __syncthreads();
    for (int d = 1; d < 128; d <<= 1) {
        int x = (t >= d && t < 128) ? exc[t - d] : 0;
        __syncthreads();
        if (t < 128) exc[t] += x;
        __syncthreads();
    }
    if (t < 128) {
        int ex = exc[t] - cnt[t];
        cur[t] = ex;
        if (t < nn) offsets[n0 + t] = p0 + ex;
    }
    if (b == 0 && t == 0) offsets[N] = E;
    __syncthreads();
    for (int i = p0 + t; i < p1; i += 256) {
        int pr = pairs[i];
        int pos = p0 + atomicAdd(&cur[pr & 127], 1);
        perm[pos] = pr >> BSH;
    }
}

// ---------- edge transform + per-node gather-sum v5 (R18 exact) ----------
__global__ __launch_bounds__(256) void edge_accum_kernel(
        const float* __restrict__ m, const float* __restrict__ rbf,
        const int* __restrict__ perm, const int* __restrict__ offsets,
        const float* __restrict__ W_rbf, uint2* __restrict__ t_pack, int N) {
    const int lane = threadIdx.x & 63;
    const int h = lane >> 5;
    const int c = lane & 31;
    const int gw = blockIdx.x * (blockDim.x >> 6) + (threadIdx.x >> 6);
    const int nwaves = gridDim.x * (blockDim.x >> 6);

    float wk[4][6];
#pragma unroll
    for (int k = 0; k < 4; ++k)
#pragma unroll
        for (int j = 0; j < 6; ++j) wk[k][j] = W_rbf[(4 * c + k) * NRAD + j];

    for (int node = gw; node < N; node += nwaves) {
        const int beg = offsets[node], end = offsets[node + 1];
        float a0 = 0.f, a1 = 0.f, a2 = 0.f, a3 = 0.f;
        int pe = 0;
        if (beg < end) {
            int pi = beg + (lane & 31); if (pi > end - 1) pi = end - 1;
            pe = perm[pi];
        }
        for (int cb = beg; cb < end; cb += 32) {
            int pe_next = 0;
            if (cb + 32 < end) {
                int pi = cb + 32 + (lane & 31); if (pi > end - 1) pi = end - 1;
                pe_next = perm[pi];
            }
            const int rem = end - cb;
            const int np = (rem >= 32) ? 16 : ((rem + 1) >> 1);
#pragma unroll 4
            for (int p = 0; p < np; ++p) {
                int e = __shfl(pe, 2 * p + h);
                const float2* rp = (const float2*)(rbf + (size_t)e * NRAD);
                float2 r0 = rp[0], r1 = rp[1], r2 = rp[2];
                float4 mv = *(const float4*)(m + (size_t)e * EMB + 4 * c);
                float g = (2 * p + h < rem) ? 1.f : 0.f;
                float p0 = (wk[0][0]*r0.x + wk[0][1]*r0.y + wk[0][2]*r1.x
                          + wk[0][3]*r1.y + wk[0][4]*r2.x + wk[0][5]*r2.y) * g;
                float p1 = (wk[1][0]*r0.x + wk[1][1]*r0.y + wk[1][2]*r1.x
                          + wk[1][3]*r1.y + wk[1][4]*r2.x + wk[1][5]*r2.y) * g;
                float p2 = (wk[2][0]*r0.x + wk[2][1]*r0.y + wk[2][2]*r1.x
                          + wk[2][3]*r1.y + wk[2][4]*r2.x + wk[2][5]*r2.y) * g;
                float p3 = (wk[3][0]*r0.x + wk[3][1]*r0.y + wk[3][2]*r1.x
                          + wk[3][3]*r1.y + wk[3][4]*r2.x + wk[3][5]*r2.y) * g;
                a0 = fmaf(mv.x, p0, a0);
                a1 = fmaf(mv.y, p1, a1);
                a2 = fmaf(mv.z, p2, a2);
                a3 = fmaf(mv.w, p3, a3);
            }
            pe = pe_next;
        }
        a0 += __shfl_xor(a0, 32);
        a1 += __shfl_xor(a1, 32);
        a2 += __shfl_xor(a2, 32);
        a3 += __shfl_xor(a3, 32);
        if (h == 0) {
            uint2 pk;
            pk.x = (unsigned)f32_to_bf16(a0) | ((unsigned)f32_to_bf16(a1) << 16);
            pk.y = (unsigned)f32_to_bf16(a2) | ((unsigned)f32_to_bf16(a3) << 16);
            t_pack[(size_t)node * 32 + c] = pk;
        }
    }
}

// ---------- fused MLP v5: 128-row blocks, 8 waves, 96KB LDS ----------
// Same per-round structure/swizzles as R15/R18; block count halves (391) so
// weight-staging rounds chip-wide halve. Occupancy unchanged (8 waves/CU).
__global__ __launch_bounds__(512) void fused_mlp2_kernel(
        const unsigned short* __restrict__ A0,    // [M,128] bf16
        const unsigned short* __restrict__ Wup,   // [256,128] bf16
        const unsigned short* __restrict__ Wd,    // [3,256,256] bf16
        const float* __restrict__ bd,             // [3,256]
        const int* __restrict__ gids,             // [M] sorted
        float* __restrict__ out, int M) {
    __shared__ char Abuf[65536];   // 128 rows x 512B (layer0: x256B)
    __shared__ char Wbuf[32768];   // 256 out-rows x 128B (one 64-K chunk)
    const int t    = threadIdx.x;
    const int w    = t >> 6;          // 0..7
    const int lane = t & 63;
    const int r    = lane & 15;
    const int g    = lane >> 4;
    const int wrh  = (w >> 2) * 64;   // row half base: 0 or 64
    const int wc   = w & 3;           // col quarter
    const int row0 = blockIdx.x * 128;

    f32x4 acc[4][4];

    // ---- stage A0: 128 rows x 256B (pre-swizzled source, linear dest) ----
#pragma unroll
    for (int it = 0; it < 4; ++it) {
        int unit = it * 512 + t;           // 0..2047
        int row  = unit >> 4;              // 0..127
        int seg  = unit & 15;
        int csrc = (seg * 16) ^ ((row & 7) << 4);
        int ga = row0 + row; if (ga >= M) ga = M - 1;
        gload_lds16((const char*)A0 + (size_t)ga * 256 + csrc, Abuf + unit * 16);
    }

    // ---- layer 0: K=128, 2 chunks of 64-K ----
#pragma unroll
    for (int i = 0; i < 4; ++i)
#pragma unroll
        for (int j = 0; j < 4; ++j) acc[i][j] = (f32x4){0.f, 0.f, 0.f, 0.f};
#pragma unroll
    for (int kci = 0; kci < 2; ++kci) {
        const int kc = kci * 64;
        if (kci) __syncthreads();
#pragma unroll
        for (int it = 0; it < 4; ++it) {
            int unit = it * 512 + t;       // 0..2047
            int wrow = unit >> 3;          // 0..255
            int seg  = unit & 7;
            int csrc = (seg * 16) ^ ((wrow & 7) << 4);
            gload_lds16((const char*)Wup + (size_t)wrow * 256 + kc * 2 + csrc,
                        Wbuf + unit * 16);
        }
        asm volatile("s_waitcnt vmcnt(0)" ::: "memory");
        __syncthreads();
#pragma unroll
        for (int ks = 0; ks < 2; ++ks) {
            short8 af[4], bf[4];
#pragma unroll
            for (int mi = 0; mi < 4; ++mi) {
                int row = wrh + mi * 16 + r;
                int off = kc * 2 + ks * 64 + g * 16;
                af[mi] = *(const short8*)(Abuf + row * 256 + (off ^ ((row & 7) << 4)));
            }
#pragma unroll
            for (int nj = 0; nj < 4; ++nj) {
                int col = wc * 64 + nj * 16 + r;
                bf[nj] = *(const short8*)(Wbuf + col * 128
                          + ((ks * 64 + g * 16) ^ ((col & 7) << 4)));
            }
#pragma unroll
            for (int mi = 0; mi < 4; ++mi)
#pragma unroll
                for (int nj = 0; nj < 4; ++nj)
                    acc[mi][nj] = __builtin_amdgcn_mfma_f32_16x16x32_bf16(
                        af[mi], bf[nj], acc[mi][nj], 0, 0, 0);
        }
    }
    __syncthreads();
#pragma unroll
    for (int mi = 0; mi < 4; ++mi)
#pragma unroll
        for (int nj = 0; nj < 4; ++nj)
#pragma unroll
            for (int q = 0; q < 4; ++q) {
                int row = wrh + mi * 16 + g * 4 + q;
                int col = wc * 64 + nj * 16 + r;
                *(unsigned short*)(Abuf + row * 512 + ((col * 2) ^ ((row & 7) << 4)))
                    = f32_to_bf16(acc[mi][nj][q]);
            }
    __syncthreads();

    // ---- layers 1..3: K=256, 4 chunks of 64-K ----
    for (int ell = 0; ell < NDENSE; ++ell) {
        const unsigned short* Wl = Wd + (size_t)ell * OUT * OUT;
        const float* bias = bd + ell * OUT;
#pragma unroll
        for (int i = 0; i < 4; ++i)
#pragma unroll
            for (int j = 0; j < 4; ++j) acc[i][j] = (f32x4){0.f, 0.f, 0.f, 0.f};
#pragma unroll
        for (int kci = 0; kci < 4; ++kci) {
            const int kc = kci * 64;
            __syncthreads();
#pragma unroll
            for (int it = 0; it < 4; ++it) {
                int unit = it * 512 + t;
                int wrow = unit >> 3;
                int seg  = unit & 7;
                int csrc = (seg * 16) ^ ((wrow & 7) << 4);
                gload_lds16((const char*)Wl + (size_t)wrow * 512 + kc * 2 + csrc,
                            Wbuf + unit * 16);
            }
            asm volatile("s_waitcnt vmcnt(0)" ::: "memory");
            __syncthreads();
#pragma unroll
            for (int ks = 0; ks < 2; ++ks) {
                short8 af[4], bf[4];
#pragma unroll
                for (int mi = 0; mi < 4; ++mi) {
                    int row = wrh + mi * 16 + r;
                    int off = kc * 2 + ks * 64 + g * 16;
                    af[mi] = *(const short8*)(Abuf + row * 512 + (off ^ ((row & 7) << 4)));
                }
#pragma unroll
                for (int nj = 0; nj < 4; ++nj) {
                    int col = wc * 64 + nj * 16 + r;
                    bf[nj] = *(const short8*)(Wbuf + col * 128
                              + ((ks * 64 + g * 16) ^ ((col & 7) << 4)));
                }
#pragma unroll
                for (int mi = 0; mi < 4; ++mi)
#pragma unroll
                    for (int nj = 0; nj < 4; ++nj)
                        acc[mi][nj] = __builtin_amdgcn_mfma_f32_16x16x32_bf16(
                            af[mi], bf[nj], acc[mi][nj], 0, 0, 0);
            }
        }
        __syncthreads();
        if (ell < NDENSE - 1) {
#pragma unroll
            for (int mi = 0; mi < 4; ++mi)
#pragma unroll
                for (int nj = 0; nj < 4; ++nj) {
                    int col = wc * 64 + nj * 16 + r;
                    float b = bias[col];
#pragma unroll
                    for (int q = 0; q < 4; ++q) {
                        int row = wrh + mi * 16 + g * 4 + q;
                        *(unsigned short*)(Abuf + row * 512
                            + ((col * 2) ^ ((row & 7) << 4)))
                            = f32_to_bf16(silu(acc[mi][nj][q] + b));
                    }
                }
            __syncthreads();
        } else {
            // ---- final layer: silu + per-graph reduce, atomicAdd into out ----
            bool uni = (row0 + 127 < M) && (gids[row0] == gids[row0 + 127]);
            if (uni) {
                int gph = gids[row0];
                float* og = out + (size_t)gph * OUT;
#pragma unroll
                for (int nj = 0; nj < 4; ++nj) {
                    int gcol = wc * 64 + nj * 16 + r;
                    float b = bias[gcol];
                    float s = 0.f;
#pragma unroll
                    for (int mi = 0; mi < 4; ++mi)
#pragma unroll
                        for (int q = 0; q < 4; ++q)
                            s += silu(acc[mi][nj][q] + b);
                    s += __shfl_xor(s, 16);
                    s += __shfl_xor(s, 32);
                    if (g == 0) atomicAdd(&og[gcol], s);
                }
            } else {
#pragma unroll
                for (int nj = 0; nj < 4; ++nj) {
                    int gcol = wc * 64 + nj * 16 + r;
                    float b = bias[gcol];
#pragma unroll
                    for (int mi = 0; mi < 4; ++mi)
#pragma unroll
                        for (int q = 0; q < 4; ++q) {
                            int grow = row0 + wrh + mi * 16 + g * 4 + q;
                            if (grow < M)
                                atomicAdd(&out[(size_t)gids[grow] * OUT + gcol],
                                          silu(acc[mi][nj][q] + b));
                        }
                }
            }
        }
    }
}

// ---------- host ----------
extern "C" void kernel_launch(void* const* d_in, const int* in_sizes, int n_in,
                              void* d_out, int out_size, void* d_ws, size_t ws_size,
                              hipStream_t stream) {
    const float* m         = (const float*)d_in[0];
    const float* rbf       = (const float*)d_in[1];
    const int*   src       = (const int*)d_in[2];
    const int*   gids      = (const int*)d_in[3];
    const float* W_rbf     = (const float*)d_in[4];
    const float* W_up      = (const float*)d_in[5];
    const float* W_dense   = (const float*)d_in[6];
    const float* b_dense   = (const float*)d_in[7];
    float* out = (float*)d_out;

    const int E = in_sizes[2];
    const int N = in_sizes[3];
    const int nbkt = (N + 127) >> BSH;     // 391 for N=50000

    size_t off = 0;
    auto alloc = [&](size_t bytes) -> void* {
        void* p = (char*)d_ws + off;
        off += (bytes + 255) & ~(size_t)255;
        return p;
    };
    int* bpart   = (int*)alloc((size_t)HB * MAXBKT * 4);
    int* bbase   = (int*)alloc((size_t)(MAXBKT + 1) * 4);
    int* gcursor = (int*)alloc((size_t)MAXBKT * 4);
    int* offsets = (int*)alloc(((size_t)N + 1) * 4);
    int* pairs   = (int*)alloc((size_t)E * 4);
    int* perm    = (int*)alloc((size_t)E * 4);
    unsigned short* t_bf = (unsigned short*)alloc((size_t)N * EMB * 2);
    unsigned short* Wbf  = (unsigned short*)alloc((size_t)(OUT * EMB + NDENSE * OUT * OUT) * 2);
    unsigned short* Wup_bf = Wbf;
    unsigned short* Wd_bf  = Wbf + OUT * EMB;

    // K0: setup = hist partials + weight convert + out zero (merged)
    setup_hist_kernel<<<HB, 256, 0, stream>>>(src, bpart, W_up, W_dense, Wbf,
                                              out, E, nbkt, out_size);
    // K1..K3: scan, scatter, local CSR
    bscan_kernel<<<1, MAXBKT, 0, stream>>>(bpart, bbase, gcursor, nbkt, E);
    bscatter_kernel<<<512, 256, 0, stream>>>(src, gcursor, pairs, E, nbkt);
    local_csr_kernel<<<nbkt, 256, 0, stream>>>(pairs, bbase, offsets, perm, N, E, nbkt);

    // edge transform + node gather v5
    edge_accum_kernel<<<2048, 256, 0, stream>>>(m, rbf, perm, offsets, W_rbf,
                                                (uint2*)t_bf, N);

    // fused MLP + per-graph readout (128-row blocks, 8 waves, 96KB LDS)
    fused_mlp2_kernel<<<(N + 127) / 128, 512, 0, stream>>>(t_bf, Wup_bf, Wd_bf,
                                                           b_dense, gids, out, N);
}

// Round 20
// 381.083 us; speedup vs baseline: 1.2143x; 1.0437x over previous
//
#include <hip/hip_runtime.h>
#include <hip/hip_bf16.h>

// ---------- types ----------
typedef __attribute__((ext_vector_type(8))) short short8;
typedef __attribute__((ext_vector_type(4))) float f32x4;

#define EMB 128
#define OUT 256
#define NRAD 6
#define NDENSE 3
#define BSH 7                 // bucket shift: 128 nodes per bucket
#define MAXBKT 512            // >= ceil(N/128)
#define HB 256                // setup/hist + scatter blocks (same partition)

static __device__ __forceinline__ unsigned short f32_to_bf16(float f) {
    union { float f; unsigned u; } v; v.f = f;
    unsigned r = v.u + 0x7fffu + ((v.u >> 16) & 1u);   // round-nearest-even
    return (unsigned short)(r >> 16);
}
static __device__ __forceinline__ float silu(float x) {
    return x / (1.f + __expf(-x));
}
static __device__ __forceinline__ void gload_lds16(const void* gp, void* lp) {
    __builtin_amdgcn_global_load_lds(
        (const __attribute__((address_space(1))) void*)gp,
        (__attribute__((address_space(3))) void*)lp, 16, 0, 0);
}
// stage one 64-K weight chunk (256 out-rows x 128B) into dst, pre-swizzled src
static __device__ __forceinline__ void stage_w(const char* Wsrc, int rowBytes,
                                               int kcByte, char* dst, int t) {
#pragma unroll
    for (int it = 0; it < 4; ++it) {
        int unit = it * 512 + t;           // 0..2047
        int wrow = unit >> 3;              // 0..255
        int seg  = unit & 7;
        int csrc = (seg * 16) ^ ((wrow & 7) << 4);
        gload_lds16(Wsrc + (size_t)wrow * rowBytes + kcByte + csrc, dst + unit * 16);
    }
}

// ---------- K0: setup = bucket hist partials + weight convert + out zero ----------
__global__ __launch_bounds__(256) void setup_hist_kernel(
        const int* __restrict__ src, int* __restrict__ bpart,
        const float* __restrict__ Wup, const float* __restrict__ Wd,
        unsigned short* __restrict__ Wbf, float* __restrict__ out,
        int E, int nbkt, int outn) {
    __shared__ int h[MAXBKT];
    for (int b = threadIdx.x; b < nbkt; b += 256) h[b] = 0;
    __syncthreads();
    int gtid = blockIdx.x * blockDim.x + threadIdx.x;
    int stride = gridDim.x * blockDim.x;
    for (int e = gtid; e < E; e += stride)
        atomicAdd(&h[src[e] >> BSH], 1);
    for (int j = gtid; j < outn; j += stride) out[j] = 0.f;
    const int n1 = OUT * EMB, n2 = NDENSE * OUT * OUT;
    for (int j = gtid; j < n1 + n2; j += stride)
        Wbf[j] = f32_to_bf16(j < n1 ? Wup[j] : Wd[j - n1]);
    __syncthreads();
    int* row = bpart + (size_t)blockIdx.x * MAXBKT;
    for (int b = threadIdx.x; b < nbkt; b += 256) row[b] = h[b];
}

// ---------- K1: convert bpart to per-block exclusive prefixes + bbase ----------
__global__ __launch_bounds__(512) void bscan_kernel(
        int* __restrict__ bpart, int* __restrict__ bbase, int nbkt, int E) {
    __shared__ int s[MAXBKT];
    int t = threadIdx.x;
    int v = 0;
    if (t < nbkt) {
        for (int k = 0; k < HB; ++k) {
            int x = bpart[(size_t)k * MAXBKT + t];
            bpart[(size_t)k * MAXBKT + t] = v;   // exclusive prefix over blocks
            v += x;
        }
    }
    s[t] = v;
    __syncthreads();
    for (int d = 1; d < MAXBKT; d <<= 1) {
        int x = (t >= d) ? s[t - d] : 0;
        __syncthreads();
        s[t] += x;
        __syncthreads();
    }
    if (t < nbkt) bbase[t] = s[t] - v;           // exclusive over buckets
    if (t == 0) bbase[nbkt] = E;
}

// ---------- K2: scatter edges using precomputed per-block bases ----------
// Same grid-stride partition as setup_hist; no hist pass, no global cursor.
__global__ __launch_bounds__(256) void bscatter_kernel(
        const int* __restrict__ src, const int* __restrict__ bpart,
        const int* __restrict__ bbase, int* __restrict__ pairs, int E, int nbkt) {
    __shared__ int base[MAXBKT];
    const int b = blockIdx.x;
    const int* myrow = bpart + (size_t)b * MAXBKT;
    for (int bb = threadIdx.x; bb < nbkt; bb += 256)
        base[bb] = myrow[bb] + bbase[bb];
    __syncthreads();
    int gtid = b * 256 + threadIdx.x, gs = HB * 256;
    for (int e = gtid; e < E; e += gs) {
        int s = src[e];
        int pos = atomicAdd(&base[s >> BSH], 1);
        pairs[pos] = (e << BSH) | (s & ((1 << BSH) - 1));
    }
}

// ---------- K3: per-bucket local CSR (counting sort in LDS)  [R19 exact] ----------
__global__ __launch_bounds__(256) void local_csr_kernel(
        const int* __restrict__ pairs, const int* __restrict__ bbase,
        int* __restrict__ offsets, int* __restrict__ perm, int N, int E, int nbkt) {
    __shared__ int cnt[128], exc[128], cur[128];
    const int b = blockIdx.x;
    const int t = threadIdx.x;
    const int n0 = b << BSH;
    const int nn = min(128, N - n0);
    const int p0 = bbase[b], p1 = bbase[b + 1];
    if (t < 128) cnt[t] = 0;
    __syncthreads();
    for (int i = p0 + t; i < p1; i += 256)
        atomicAdd(&cnt[pairs[i] & 127], 1);
    __syncthreads();
    if (t < 128) exc[t] = cnt[t];
    __syncthreads();
    for (int d = 1; d < 128; d <<= 1) {
        int x = (t >= d && t < 128) ? exc[t - d] : 0;
        __syncthreads();
        if (t < 128) exc[t] += x;
        __syncthreads();
    }
    if (t < 128) {
        int ex = exc[t] - cnt[t];
        cur[t] = ex;
        if (t < nn) offsets[n0 + t] = p0 + ex;
    }
    if (b == 0 && t == 0) offsets[N] = E;
    __syncthreads();
    for (int i = p0 + t; i < p1; i += 256) {
        int pr = pairs[i];
        int pos = p0 + atomicAdd(&cur[pr & 127], 1);
        perm[pos] = pr >> BSH;
    }
}

// ---------- edge transform + per-node gather-sum v5  [R19 exact] ----------
__global__ __launch_bounds__(256) void edge_accum_kernel(
        const float* __restrict__ m, const float* __restrict__ rbf,
        const int* __restrict__ perm, const int* __restrict__ offsets,
        const float* __restrict__ W_rbf, uint2* __restrict__ t_pack, int N) {
    const int lane = threadIdx.x & 63;
    const int h = lane >> 5;
    const int c = lane & 31;
    const int gw = blockIdx.x * (blockDim.x >> 6) + (threadIdx.x >> 6);
    const int nwaves = gridDim.x * (blockDim.x >> 6);

    float wk[4][6];
#pragma unroll
    for (int k = 0; k < 4; ++k)
#pragma unroll
        for (int j = 0; j < 6; ++j) wk[k][j] = W_rbf[(4 * c + k) * NRAD + j];

    for (int node = gw; node < N; node += nwaves) {
        const int beg = offsets[node], end = offsets[node + 1];
        float a0 = 0.f, a1 = 0.f, a2 = 0.f, a3 = 0.f;
        int pe = 0;
        if (beg < end) {
            int pi = beg + (lane & 31); if (pi > end - 1) pi = end - 1;
            pe = perm[pi];
        }
        for (int cb = beg; cb < end; cb += 32) {
            int pe_next = 0;
            if (cb + 32 < end) {
                int pi = cb + 32 + (lane & 31); if (pi > end - 1) pi = end - 1;
                pe_next = perm[pi];
            }
            const int rem = end - cb;
            const int np = (rem >= 32) ? 16 : ((rem + 1) >> 1);
#pragma unroll 4
            for (int p = 0; p < np; ++p) {
                int e = __shfl(pe, 2 * p + h);
                const float2* rp = (const float2*)(rbf + (size_t)e * NRAD);
                float2 r0 = rp[0], r1 = rp[1], r2 = rp[2];
                float4 mv = *(const float4*)(m + (size_t)e * EMB + 4 * c);
                float g = (2 * p + h < rem) ? 1.f : 0.f;
                float p0 = (wk[0][0]*r0.x + wk[0][1]*r0.y + wk[0][2]*r1.x
                          + wk[0][3]*r1.y + wk[0][4]*r2.x + wk[0][5]*r2.y) * g;
                float p1 = (wk[1][0]*r0.x + wk[1][1]*r0.y + wk[1][2]*r1.x
                          + wk[1][3]*r1.y + wk[1][4]*r2.x + wk[1][5]*r2.y) * g;
                float p2 = (wk[2][0]*r0.x + wk[2][1]*r0.y + wk[2][2]*r1.x
                          + wk[2][3]*r1.y + wk[2][4]*r2.x + wk[2][5]*r2.y) * g;
                float p3 = (wk[3][0]*r0.x + wk[3][1]*r0.y + wk[3][2]*r1.x
                          + wk[3][3]*r1.y + wk[3][4]*r2.x + wk[3][5]*r2.y) * g;
                a0 = fmaf(mv.x, p0, a0);
                a1 = fmaf(mv.y, p1, a1);
                a2 = fmaf(mv.z, p2, a2);
                a3 = fmaf(mv.w, p3, a3);
            }
            pe = pe_next;
        }
        a0 += __shfl_xor(a0, 32);
        a1 += __shfl_xor(a1, 32);
        a2 += __shfl_xor(a2, 32);
        a3 += __shfl_xor(a3, 32);
        if (h == 0) {
            uint2 pk;
            pk.x = (unsigned)f32_to_bf16(a0) | ((unsigned)f32_to_bf16(a1) << 16);
            pk.y = (unsigned)f32_to_bf16(a2) | ((unsigned)f32_to_bf16(a3) << 16);
            t_pack[(size_t)node * 32 + c] = pk;
        }
    }
}

// ---------- fused MLP v6: 128-row blocks, double-buffered Wbuf prefetch ----------
// Per chunk: vmcnt(0); sync; issue(next chunk)->other buf; compute(cur buf).
// Load latency hides under 32 MFMAs; 1 barrier/chunk instead of 2. Next layer's
// chunk0 issue overlaps the Abuf write-back. LDS = 64K Abuf + 2x32K Wbuf = 128K.
__global__ __launch_bounds__(512) void fused_mlp2_kernel(
        const unsigned short* __restrict__ A0,    // [M,128] bf16
        const unsigned short* __restrict__ Wup,   // [256,128] bf16
        const unsigned short* __restrict__ Wd,    // [3,256,256] bf16
        const float* __restrict__ bd,             // [3,256]
        const int* __restrict__ gids,             // [M] sorted
        float* __restrict__ out, int M) {
    __shared__ char Abuf[65536];       // 128 rows x 512B (layer0: x256B)
    __shared__ char Wbuf[2][32768];    // double-buffered 64-K weight chunk
    const int t    = threadIdx.x;
    const int w    = t >> 6;          // 0..7
    const int lane = t & 63;
    const int r    = lane & 15;
    const int g    = lane >> 4;
    const int wrh  = (w >> 2) * 64;   // row half base: 0 or 64
    const int wc   = w & 3;           // col quarter
    const int row0 = blockIdx.x * 128;

    f32x4 acc[4][4];

    // ---- stage A0: 128 rows x 256B (pre-swizzled source, linear dest) ----
#pragma unroll
    for (int it = 0; it < 4; ++it) {
        int unit = it * 512 + t;
        int row  = unit >> 4;
        int seg  = unit & 15;
        int csrc = (seg * 16) ^ ((row & 7) << 4);
        int ga = row0 + row; if (ga >= M) ga = M - 1;
        gload_lds16((const char*)A0 + (size_t)ga * 256 + csrc, Abuf + unit * 16);
    }

    int p = 0;
    stage_w((const char*)Wup, 256, 0, Wbuf[0], t);   // layer0 chunk0

    // ---- layer 0: K=128, 2 chunks of 64-K ----
#pragma unroll
    for (int i = 0; i < 4; ++i)
#pragma unroll
        for (int j = 0; j < 4; ++j) acc[i][j] = (f32x4){0.f, 0.f, 0.f, 0.f};
#pragma unroll
    for (int kci = 0; kci < 2; ++kci) {
        const int kc = kci * 64;
        asm volatile("s_waitcnt vmcnt(0)" ::: "memory");
        __syncthreads();
        if (kci + 1 < 2)
            stage_w((const char*)Wup, 256, (kci + 1) * 128, Wbuf[p ^ 1], t);
#pragma unroll
        for (int ks = 0; ks < 2; ++ks) {
            short8 af[4], bf[4];
#pragma unroll
            for (int mi = 0; mi < 4; ++mi) {
                int row = wrh + mi * 16 + r;
                int off = kc * 2 + ks * 64 + g * 16;
                af[mi] = *(const short8*)(Abuf + row * 256 + (off ^ ((row & 7) << 4)));
            }
#pragma unroll
            for (int nj = 0; nj < 4; ++nj) {
                int col = wc * 64 + nj * 16 + r;
                bf[nj] = *(const short8*)(Wbuf[p] + col * 128
                          + ((ks * 64 + g * 16) ^ ((col & 7) << 4)));
            }
#pragma unroll
            for (int mi = 0; mi < 4; ++mi)
#pragma unroll
                for (int nj = 0; nj < 4; ++nj)
                    acc[mi][nj] = __builtin_amdgcn_mfma_f32_16x16x32_bf16(
                        af[mi], bf[nj], acc[mi][nj], 0, 0, 0);
        }
        p ^= 1;
    }
    // issue layer-1 chunk0 early (overlaps Abuf write-back); Wbuf[p] free
    stage_w((const char*)Wd, 512, 0, Wbuf[p], t);
    __syncthreads();                   // all Abuf(256B) reads done
#pragma unroll
    for (int mi = 0; mi < 4; ++mi)
#pragma unroll
        for (int nj = 0; nj < 4; ++nj)
#pragma unroll
            for (int q = 0; q < 4; ++q) {
                int row = wrh + mi * 16 + g * 4 + q;
                int col = wc * 64 + nj * 16 + r;
                *(unsigned short*)(Abuf + row * 512 + ((col * 2) ^ ((row & 7) << 4)))
                    = f32_to_bf16(acc[mi][nj][q]);
            }
    __syncthreads();

    // ---- layers 1..3: K=256, 4 chunks of 64-K ----
    for (int ell = 0; ell < NDENSE; ++ell) {
        const char* Wl = (const char*)(Wd + (size_t)ell * OUT * OUT);
        const float* bias = bd + ell * OUT;
#pragma unroll
        for (int i = 0; i < 4; ++i)
#pragma unroll
            for (int j = 0; j < 4; ++j) acc[i][j] = (f32x4){0.f, 0.f, 0.f, 0.f};
#pragma unroll
        for (int kci = 0; kci < 4; ++kci) {
            const int kc = kci * 64;
            asm volatile("s_waitcnt vmcnt(0)" ::: "memory");
            __syncthreads();
            if (kci + 1 < 4)
                stage_w(Wl, 512, (kci + 1) * 128, Wbuf[p ^ 1], t);
#pragma unroll
            for (int ks = 0; ks < 2; ++ks) {
                short8 af[4], bf[4];
#pragma unroll
                for (int mi = 0; mi < 4; ++mi) {
                    int row = wrh + mi * 16 + r;
                    int off = kc * 2 + ks * 64 + g * 16;
                    af[mi] = *(const short8*)(Abuf + row * 512 + (off ^ ((row & 7) << 4)));
                }
#pragma unroll
                for (int nj = 0; nj < 4; ++nj) {
                    int col = wc * 64 + nj * 16 + r;
                    bf[nj] = *(const short8*)(Wbuf[p] + col * 128
                              + ((ks * 64 + g * 16) ^ ((col & 7) << 4)));
                }
#pragma unroll
                for (int mi = 0; mi < 4; ++mi)
#pragma unroll
                    for (int nj = 0; nj < 4; ++nj)
                        acc[mi][nj] = __builtin_amdgcn_mfma_f32_16x16x32_bf16(
                            af[mi], bf[nj], acc[mi][nj], 0, 0, 0);
            }
            p ^= 1;
        }
        if (ell < NDENSE - 1) {
            // issue next layer chunk0 early; Wbuf[p] had its last read 2 chunks ago
            stage_w((const char*)(Wd + (size_t)(ell + 1) * OUT * OUT), 512, 0,
                    Wbuf[p], t);
            __syncthreads();            // all Abuf reads done
#pragma unroll
            for (int mi = 0; mi < 4; ++mi)
#pragma unroll
                for (int nj = 0; nj < 4; ++nj) {
                    int col = wc * 64 + nj * 16 + r;
                    float b = bias[col];
#pragma unroll
                    for (int q = 0; q < 4; ++q) {
                        int row = wrh + mi * 16 + g * 4 + q;
                        *(unsigned short*)(Abuf + row * 512
                            + ((col * 2) ^ ((row & 7) << 4)))
                            = f32_to_bf16(silu(acc[mi][nj][q] + b));
                    }
                }
            __syncthreads();
        } else {
            // ---- final layer: silu + per-graph reduce, atomicAdd into out ----
            bool uni = (row0 + 127 < M) && (gids[row0] == gids[row0 + 127]);
            if (uni) {
                int gph = gids[row0];
                float* og = out + (size_t)gph * OUT;
#pragma unroll
                for (int nj = 0; nj < 4; ++nj) {
                    int gcol = wc * 64 + nj * 16 + r;
                    float b = bias[gcol];
                    float s = 0.f;
#pragma unroll
                    for (int mi = 0; mi < 4; ++mi)
#pragma unroll
                        for (int q = 0; q < 4; ++q)
                            s += silu(acc[mi][nj][q] + b);
                    s += __shfl_xor(s, 16);
                    s += __shfl_xor(s, 32);
                    if (g == 0) atomicAdd(&og[gcol], s);
                }
            } else {
#pragma unroll
                for (int nj = 0; nj < 4; ++nj) {
                    int gcol = wc * 64 + nj * 16 + r;
                    float b = bias[gcol];
#pragma unroll
                    for (int mi = 0; mi < 4; ++mi)
#pragma unroll
                        for (int q = 0; q < 4; ++q) {
                            int grow = row0 + wrh + mi * 16 + g * 4 + q;
                            if (grow < M)
                                atomicAdd(&out[(size_t)gids[grow] * OUT + gcol],
                                          silu(acc[mi][nj][q] + b));
                        }
                }
            }
        }
    }
}

// ---------- host ----------
extern "C" void kernel_launch(void* const* d_in, const int* in_sizes, int n_in,
                              void* d_out, int out_size, void* d_ws, size_t ws_size,
                              hipStream_t stream) {
    const float* m         = (const float*)d_in[0];
    const float* rbf       = (const float*)d_in[1];
    const int*   src       = (const int*)d_in[2];
    const int*   gids      = (const int*)d_in[3];
    const float* W_rbf     = (const float*)d_in[4];
    const float* W_up      = (const float*)d_in[5];
    const float* W_dense   = (const float*)d_in[6];
    const float* b_dense   = (const float*)d_in[7];
    float* out = (float*)d_out;

    const int E = in_sizes[2];
    const int N = in_sizes[3];
    const int nbkt = (N + 127) >> BSH;     // 391 for N=50000

    size_t off = 0;
    auto alloc = [&](size_t bytes) -> void* {
        void* p = (char*)d_ws + off;
        off += (bytes + 255) & ~(size_t)255;
        return p;
    };
    int* bpart   = (int*)alloc((size_t)HB * MAXBKT * 4);
    int* bbase   = (int*)alloc((size_t)(MAXBKT + 1) * 4);
    int* offsets = (int*)alloc(((size_t)N + 1) * 4);
    int* pairs   = (int*)alloc((size_t)E * 4);
    int* perm    = (int*)alloc((size_t)E * 4);
    unsigned short* t_bf = (unsigned short*)alloc((size_t)N * EMB * 2);
    unsigned short* Wbf  = (unsigned short*)alloc((size_t)(OUT * EMB + NDENSE * OUT * OUT) * 2);
    unsigned short* Wup_bf = Wbf;
    unsigned short* Wd_bf  = Wbf + OUT * EMB;

    // K0: setup = hist partials + weight convert + out zero
    setup_hist_kernel<<<HB, 256, 0, stream>>>(src, bpart, W_up, W_dense, Wbf,
                                              out, E, nbkt, out_size);
    // K1: in-place block-prefix + bucket scan
    bscan_kernel<<<1, MAXBKT, 0, stream>>>(bpart, bbase, nbkt, E);
    // K2: scatter with precomputed bases (no hist pass, no global cursor)
    bscatter_kernel<<<HB, 256, 0, stream>>>(src, bpart, bbase, pairs, E, nbkt);
    // K3: per-bucket local CSR
    local_csr_kernel<<<nbkt, 256, 0, stream>>>(pairs, bbase, offsets, perm, N, E, nbkt);

    // edge transform + node gather v5
    edge_accum_kernel<<<2048, 256, 0, stream>>>(m, rbf, perm, offsets, W_rbf,
                                                (uint2*)t_bf, N);

    // fused MLP + per-graph readout (128-row blocks, prefetched weights)
    fused_mlp2_kernel<<<(N + 127) / 128, 512, 0, stream>>>(t_bf, Wup_bf, Wd_bf,
                                                           b_dense, gids, out, N);
}